// Round 1
// baseline (8681.799 us; speedup 1.0000x reference)
//
#include <hip/hip_runtime.h>
#include <hip/hip_bf16.h>
#include <math.h>

// ---------------- constants ----------------
#define L_SEQ 1024
#define C_DIM 1024
#define NHEAD 16
#define DHEAD 64
#define BSZ 2

// ---------------- pos embed + input add ----------------
__global__ void posembed_kernel(const float* __restrict__ xin, float* __restrict__ xb) {
    int idx = blockIdx.x * 256 + threadIdx.x;     // 2*1024*1024
    int c = idx & 1023;
    int n = (idx >> 10) & 1023;
    int pos = (c < 512) ? (n & 31) : (n >> 5);    // first half: w (j), second: h (i)
    int cc = c & 511;
    int k = cc & 255;
    double om = exp(-(double)k * (9.210340371976184 / 256.0)); // 1/10000^(k/256)
    double arg = (double)pos * om;
    float e = (float)((cc < 256) ? sin(arg) : cos(arg));
    xb[idx] = xin[idx] + e;
}

// ---------------- layernorm over C=1024 ----------------
__global__ __launch_bounds__(256) void ln_kernel(const float* __restrict__ X,
                                                 float* __restrict__ Y,
                                                 const float* __restrict__ g,
                                                 const float* __restrict__ b,
                                                 float eps, int affine) {
    int row = blockIdx.x;
    const float4* xr = (const float4*)(X + (size_t)row * 1024);
    float4 x = xr[threadIdx.x];
    float s = x.x + x.y + x.z + x.w;
    float sq = x.x * x.x + x.y * x.y + x.z * x.z + x.w * x.w;
    __shared__ float red[8];
    #pragma unroll
    for (int off = 32; off; off >>= 1) { s += __shfl_xor(s, off); sq += __shfl_xor(sq, off); }
    int wid = threadIdx.x >> 6, lane = threadIdx.x & 63;
    if (!lane) { red[wid] = s; red[wid + 4] = sq; }
    __syncthreads();
    s = red[0] + red[1] + red[2] + red[3];
    sq = red[4] + red[5] + red[6] + red[7];
    float mu = s * (1.f / 1024.f);
    float var = sq * (1.f / 1024.f) - mu * mu;
    float rs = rsqrtf(var + eps);
    int c = threadIdx.x * 4;
    float4 y;
    if (affine) {
        y.x = (x.x - mu) * rs * g[c + 0] + b[c + 0];
        y.y = (x.y - mu) * rs * g[c + 1] + b[c + 1];
        y.z = (x.z - mu) * rs * g[c + 2] + b[c + 2];
        y.w = (x.w - mu) * rs * g[c + 3] + b[c + 3];
    } else {
        y.x = (x.x - mu) * rs; y.y = (x.y - mu) * rs;
        y.z = (x.z - mu) * rs; y.w = (x.w - mu) * rs;
    }
    ((float4*)(Y + (size_t)row * 1024))[threadIdx.x] = y;
}

// ---------------- qk-norm (LN over d=64, per (b,l,head), shared g/b across heads) ----
__global__ __launch_bounds__(256) void qknorm_kernel(float* __restrict__ qkv,
                                                     const float* __restrict__ nqg,
                                                     const float* __restrict__ nqb,
                                                     const float* __restrict__ nkg,
                                                     const float* __restrict__ nkb) {
    int wid = threadIdx.x >> 6, lane = threadIdx.x & 63;
    int row = blockIdx.x * 4 + wid;        // (b*1024 + l)*16 + head
    int head = row & 15;
    int bl = row >> 4;
    float* base = qkv + (size_t)bl * 3072 + head * 64 + lane;
    #pragma unroll
    for (int part = 0; part < 2; part++) {
        float* p = base + part * 1024;
        float v = *p;
        float s = v, sq = v * v;
        #pragma unroll
        for (int off = 32; off; off >>= 1) { s += __shfl_xor(s, off); sq += __shfl_xor(sq, off); }
        float mu = s * (1.f / 64.f);
        float var = sq * (1.f / 64.f) - mu * mu;
        float rs = rsqrtf(var + 1e-5f);
        const float* gg = part ? nkg : nqg;
        const float* bb = part ? nkb : nqb;
        *p = (v - mu) * rs * gg[lane] + bb[lane];
    }
}

// ---------------- attention: one block per (qtile of 8, head, b) -------------
#define QT 8
__global__ __launch_bounds__(256) void attn_kernel(const float* __restrict__ qkv,
                                                   float* __restrict__ ob) {
    __shared__ float S[QT][1024];
    __shared__ float Qs[QT][64];
    __shared__ float red[8];
    int tid = threadIdx.x;
    int b = blockIdx.z, head = blockIdx.y, q0 = blockIdx.x * QT;
    const float* base = qkv + (size_t)b * L_SEQ * 3072 + head * 64;
    for (int i = tid; i < QT * 64; i += 256) {
        int r = i >> 6, dd = i & 63;
        Qs[r][dd] = base[(size_t)(q0 + r) * 3072 + dd];
    }
    __syncthreads();
    // phase 1: S = Q K^T * scale
    for (int it = 0; it < 4; it++) {
        int l = tid + it * 256;
        const float* krow = base + (size_t)l * 3072 + 1024;
        float acc[QT];
        #pragma unroll
        for (int r = 0; r < QT; r++) acc[r] = 0.f;
        for (int dd = 0; dd < 64; dd += 4) {
            float4 kv = *(const float4*)(krow + dd);
            #pragma unroll
            for (int r = 0; r < QT; r++)
                acc[r] += Qs[r][dd] * kv.x + Qs[r][dd + 1] * kv.y +
                          Qs[r][dd + 2] * kv.z + Qs[r][dd + 3] * kv.w;
        }
        #pragma unroll
        for (int r = 0; r < QT; r++) S[r][l] = acc[r] * 0.125f;
    }
    __syncthreads();
    // phase 2: softmax each row
    int wid = tid >> 6, lane = tid & 63;
    for (int r = 0; r < QT; r++) {
        float m = -1e30f;
        #pragma unroll
        for (int it = 0; it < 4; it++) m = fmaxf(m, S[r][tid + it * 256]);
        #pragma unroll
        for (int off = 32; off; off >>= 1) m = fmaxf(m, __shfl_xor(m, off));
        if (!lane) red[wid] = m;
        __syncthreads();
        m = fmaxf(fmaxf(red[0], red[1]), fmaxf(red[2], red[3]));
        float s = 0.f;
        #pragma unroll
        for (int it = 0; it < 4; it++) {
            float e = __expf(S[r][tid + it * 256] - m);
            S[r][tid + it * 256] = e;
            s += e;
        }
        #pragma unroll
        for (int off = 32; off; off >>= 1) s += __shfl_xor(s, off);
        if (!lane) red[wid + 4] = s;
        __syncthreads();
        s = red[4] + red[5] + red[6] + red[7];
        float inv = 1.f / s;
        #pragma unroll
        for (int it = 0; it < 4; it++) S[r][tid + it * 256] *= inv;
        __syncthreads();
    }
    // phase 3: O = P V   (thread: dd = tid&63, rows rg and rg+4)
    int dd = tid & 63, rg = tid >> 6;
    const float* vbase = base + 2048 + dd;
    float a0 = 0.f, a1 = 0.f;
    for (int l = 0; l < 1024; l++) {
        float v = vbase[(size_t)l * 3072];
        a0 += S[rg][l] * v;
        a1 += S[rg + 4][l] * v;
    }
    float* obase = ob + ((size_t)b * L_SEQ + q0) * 1024 + head * 64 + dd;
    obase[(size_t)rg * 1024] = a0;
    obase[(size_t)(rg + 4) * 1024] = a1;
}

// ---------------- tiled fp32 GEMM: C = act(A@B + bias) [+ C] ------------------
// A: MxK row-major, B: KxN row-major. 256 threads.
template <int BM, int BN, int TM, int TN, int ACT, bool ADDC>
__global__ __launch_bounds__(256) void gemm_kernel(const float* __restrict__ A,
                                                   const float* __restrict__ B,
                                                   const float* __restrict__ bias,
                                                   float* __restrict__ C,
                                                   int M, int N, int K) {
    const int BK = 16;
    __shared__ float As[BK][BM];
    __shared__ float Bs[BK][BN];
    int tid = threadIdx.x;
    int m0 = blockIdx.y * BM, n0 = blockIdx.x * BN;
    int tx = tid % (BN / TN), ty = tid / (BN / TN);
    float acc[TM][TN];
    #pragma unroll
    for (int i = 0; i < TM; i++)
        #pragma unroll
        for (int j = 0; j < TN; j++) acc[i][j] = 0.f;

    for (int k0 = 0; k0 < K; k0 += BK) {
        #pragma unroll
        for (int i = 0; i < BM * BK / 1024; i++) {
            int idx = tid + i * 256;
            int r = idx / (BK / 4), c4 = idx % (BK / 4);
            float4 a = *(const float4*)(A + (size_t)(m0 + r) * K + k0 + c4 * 4);
            As[c4 * 4 + 0][r] = a.x; As[c4 * 4 + 1][r] = a.y;
            As[c4 * 4 + 2][r] = a.z; As[c4 * 4 + 3][r] = a.w;
        }
        #pragma unroll
        for (int i = 0; i < BK * BN / 1024; i++) {
            int idx = tid + i * 256;
            int r = idx / (BN / 4), c4 = idx % (BN / 4);
            *(float4*)&Bs[r][c4 * 4] = *(const float4*)(B + (size_t)(k0 + r) * N + n0 + c4 * 4);
        }
        __syncthreads();
        #pragma unroll
        for (int k = 0; k < BK; k++) {
            float ar[TM], br[TN];
            #pragma unroll
            for (int i = 0; i < TM; i++) ar[i] = As[k][ty * TM + i];
            #pragma unroll
            for (int j = 0; j < TN; j++) br[j] = Bs[k][tx * TN + j];
            #pragma unroll
            for (int i = 0; i < TM; i++)
                #pragma unroll
                for (int j = 0; j < TN; j++) acc[i][j] += ar[i] * br[j];
        }
        __syncthreads();
    }
    #pragma unroll
    for (int i = 0; i < TM; i++) {
        int m = m0 + ty * TM + i;
        #pragma unroll
        for (int j = 0; j < TN; j++) {
            int n = n0 + tx * TN + j;
            float v = acc[i][j] + bias[n];
            if (ACT == 1) v = 0.5f * v * (1.f + erff(v * 0.70710678118654752f));
            if (ADDC) v += C[(size_t)m * N + n];
            C[(size_t)m * N + n] = v;
        }
    }
}

// ---------------- unpatchify ----------------
__global__ void unpatchify_kernel(const float* __restrict__ xf, float* __restrict__ img) {
    int idx = blockIdx.x * 256 + threadIdx.x;   // 2*64*64*64
    int x = idx & 63, y = (idx >> 6) & 63, ch = (idx >> 12) & 63, b = idx >> 18;
    int hh = y >> 1, ww = x >> 1, p = y & 1, q = x & 1;
    img[idx] = xf[((size_t)b * 1024 + hh * 32 + ww) * 256 + ch * 4 + p * 2 + q];
}

// ---------------- conv1: 64->16 ch, 3x3, pad 1, relu ----------------
__global__ void conv1_kernel(const float* __restrict__ img, const float* __restrict__ w,
                             const float* __restrict__ bias, float* __restrict__ out) {
    int idx = blockIdx.x * 256 + threadIdx.x;   // 2*16*64*64
    int x = idx & 63, y = (idx >> 6) & 63, oc = (idx >> 12) & 15, b = idx >> 16;
    const float* ib = img + (size_t)b * 64 * 64 * 64;
    float s = bias[oc];
    for (int ic = 0; ic < 64; ic++) {
        const float* ip = ib + ic * 4096;
        const float* wp = w + (oc * 64 + ic) * 9;
        #pragma unroll
        for (int ky = 0; ky < 3; ky++) {
            int yy = y + ky - 1;
            if (yy < 0 || yy > 63) continue;
            #pragma unroll
            for (int kx = 0; kx < 3; kx++) {
                int xx = x + kx - 1;
                if (xx < 0 || xx > 63) continue;
                s += ip[yy * 64 + xx] * wp[ky * 3 + kx];
            }
        }
    }
    out[idx] = fmaxf(s, 0.f);
}

// ---------------- conv2: 16->3 ch, 3x3, pad 1 ----------------
__global__ void conv2_kernel(const float* __restrict__ in, const float* __restrict__ w,
                             const float* __restrict__ bias, float* __restrict__ out) {
    int idx = blockIdx.x * 256 + threadIdx.x;   // 2*3*64*64 = 24576
    if (idx >= 24576) return;
    int x = idx & 63, y = (idx >> 6) & 63;
    int t = idx >> 12;
    int oc = t % 3, b = t / 3;
    const float* ib = in + (size_t)b * 16 * 4096;
    float s = bias[oc];
    for (int ic = 0; ic < 16; ic++) {
        const float* ip = ib + ic * 4096;
        const float* wp = w + (oc * 16 + ic) * 9;
        #pragma unroll
        for (int ky = 0; ky < 3; ky++) {
            int yy = y + ky - 1;
            if (yy < 0 || yy > 63) continue;
            #pragma unroll
            for (int kx = 0; kx < 3; kx++) {
                int xx = x + kx - 1;
                if (xx < 0 || xx > 63) continue;
                s += ip[yy * 64 + xx] * wp[ky * 3 + kx];
            }
        }
    }
    out[idx] = s;
}

// ---------------- launch ----------------
extern "C" void kernel_launch(void* const* d_in, const int* in_sizes, int n_in,
                              void* d_out, int out_size, void* d_ws, size_t ws_size,
                              hipStream_t stream) {
    const float* x_in   = (const float*)d_in[0];
    const float* qkv_w  = (const float*)d_in[1];
    const float* qkv_b  = (const float*)d_in[2];
    const float* proj_w = (const float*)d_in[3];
    const float* proj_b = (const float*)d_in[4];
    const float* nq_g   = (const float*)d_in[5];
    const float* nq_b   = (const float*)d_in[6];
    const float* nk_g   = (const float*)d_in[7];
    const float* nk_b   = (const float*)d_in[8];
    const float* n1_g   = (const float*)d_in[9];
    const float* n1_b   = (const float*)d_in[10];
    const float* n2_g   = (const float*)d_in[11];
    const float* n2_b   = (const float*)d_in[12];
    const float* fc1_w  = (const float*)d_in[13];
    const float* fc1_b  = (const float*)d_in[14];
    const float* fc2_w  = (const float*)d_in[15];
    const float* fc2_b  = (const float*)d_in[16];
    const float* fin_w  = (const float*)d_in[17];
    const float* fin_b  = (const float*)d_in[18];
    const float* c1_w   = (const float*)d_in[19];
    const float* c1_b   = (const float*)d_in[20];
    const float* c2_w   = (const float*)d_in[21];
    const float* c2_b   = (const float*)d_in[22];
    float* out = (float*)d_out;

    char* w = (char*)d_ws;
    float* xb  = (float*)w; w += (size_t)2 * 1024 * 1024 * 4;      // residual stream
    float* hn  = (float*)w; w += (size_t)2 * 1024 * 1024 * 4;      // LN out
    float* qkv = (float*)w; w += (size_t)2 * 1024 * 3072 * 4;
    float* ob  = (float*)w; w += (size_t)2 * 1024 * 1024 * 4;      // attn out
    float* mh  = (float*)w; w += (size_t)2 * 1024 * 4096 * 4;      // mlp hidden
    float* xf  = (float*)w; w += (size_t)2 * 1024 * 256 * 4;
    float* img = (float*)w; w += (size_t)2 * 64 * 64 * 64 * 4;
    float* c1o = (float*)w; w += (size_t)2 * 16 * 64 * 64 * 4;

    posembed_kernel<<<8192, 256, 0, stream>>>(x_in, xb);

    for (int i = 0; i < 4; i++) {
        ln_kernel<<<2048, 256, 0, stream>>>(xb, hn, n1_g + i * 1024, n1_b + i * 1024, 1e-5f, 1);
        gemm_kernel<128, 128, 8, 8, 0, false><<<dim3(24, 16), 256, 0, stream>>>(
            hn, qkv_w + (size_t)i * 1024 * 3072, qkv_b + i * 3072, qkv, 2048, 3072, 1024);
        qknorm_kernel<<<8192, 256, 0, stream>>>(qkv, nq_g + i * 64, nq_b + i * 64,
                                                nk_g + i * 64, nk_b + i * 64);
        attn_kernel<<<dim3(128, 16, 2), 256, 0, stream>>>(qkv, ob);
        gemm_kernel<128, 64, 8, 4, 0, true><<<dim3(16, 16), 256, 0, stream>>>(
            ob, proj_w + (size_t)i * 1024 * 1024, proj_b + i * 1024, xb, 2048, 1024, 1024);
        ln_kernel<<<2048, 256, 0, stream>>>(xb, hn, n2_g + i * 1024, n2_b + i * 1024, 1e-5f, 1);
        gemm_kernel<128, 128, 8, 8, 1, false><<<dim3(32, 16), 256, 0, stream>>>(
            hn, fc1_w + (size_t)i * 1024 * 4096, fc1_b + i * 4096, mh, 2048, 4096, 1024);
        gemm_kernel<128, 64, 8, 4, 0, true><<<dim3(16, 16), 256, 0, stream>>>(
            mh, fc2_w + (size_t)i * 4096 * 1024, fc2_b + i * 1024, xb, 2048, 1024, 4096);
    }

    ln_kernel<<<2048, 256, 0, stream>>>(xb, hn, nullptr, nullptr, 1e-6f, 0);
    gemm_kernel<128, 64, 8, 4, 0, false><<<dim3(4, 16), 256, 0, stream>>>(
        hn, fin_w, fin_b, xf, 2048, 256, 1024);
    unpatchify_kernel<<<2048, 256, 0, stream>>>(xf, img);
    conv1_kernel<<<512, 256, 0, stream>>>(img, c1_w, c1_b, c1o);
    conv2_kernel<<<96, 256, 0, stream>>>(c1o, c2_w, c2_b, out);
}

// Round 2
// 4640.866 us; speedup vs baseline: 1.8707x; 1.8707x over previous
//
#include <hip/hip_runtime.h>
#include <hip/hip_bf16.h>
#include <math.h>

// ---------------- constants ----------------
#define L_SEQ 1024
#define C_DIM 1024
#define NHEAD 16
#define DHEAD 64
#define BSZ 2

// ---------------- pos embed + input add ----------------
__global__ void posembed_kernel(const float* __restrict__ xin, float* __restrict__ xb) {
    int idx = blockIdx.x * 256 + threadIdx.x;     // 2*1024*1024
    int c = idx & 1023;
    int n = (idx >> 10) & 1023;
    int pos = (c < 512) ? (n & 31) : (n >> 5);    // first half: w (j), second: h (i)
    int cc = c & 511;
    int k = cc & 255;
    double om = exp(-(double)k * (9.210340371976184 / 256.0)); // 1/10000^(k/256)
    double arg = (double)pos * om;
    float e = (float)((cc < 256) ? sin(arg) : cos(arg));
    xb[idx] = xin[idx] + e;
}

// ---------------- layernorm over C=1024 ----------------
__global__ __launch_bounds__(256) void ln_kernel(const float* __restrict__ X,
                                                 float* __restrict__ Y,
                                                 const float* __restrict__ g,
                                                 const float* __restrict__ b,
                                                 float eps, int affine) {
    int row = blockIdx.x;
    const float4* xr = (const float4*)(X + (size_t)row * 1024);
    float4 x = xr[threadIdx.x];
    float s = x.x + x.y + x.z + x.w;
    float sq = x.x * x.x + x.y * x.y + x.z * x.z + x.w * x.w;
    __shared__ float red[8];
    #pragma unroll
    for (int off = 32; off; off >>= 1) { s += __shfl_xor(s, off); sq += __shfl_xor(sq, off); }
    int wid = threadIdx.x >> 6, lane = threadIdx.x & 63;
    if (!lane) { red[wid] = s; red[wid + 4] = sq; }
    __syncthreads();
    s = red[0] + red[1] + red[2] + red[3];
    sq = red[4] + red[5] + red[6] + red[7];
    float mu = s * (1.f / 1024.f);
    float var = sq * (1.f / 1024.f) - mu * mu;
    float rs = rsqrtf(var + eps);
    int c = threadIdx.x * 4;
    float4 y;
    if (affine) {
        y.x = (x.x - mu) * rs * g[c + 0] + b[c + 0];
        y.y = (x.y - mu) * rs * g[c + 1] + b[c + 1];
        y.z = (x.z - mu) * rs * g[c + 2] + b[c + 2];
        y.w = (x.w - mu) * rs * g[c + 3] + b[c + 3];
    } else {
        y.x = (x.x - mu) * rs; y.y = (x.y - mu) * rs;
        y.z = (x.z - mu) * rs; y.w = (x.w - mu) * rs;
    }
    ((float4*)(Y + (size_t)row * 1024))[threadIdx.x] = y;
}

// ---------------- qk-norm (LN over d=64, per (b,l,head)) ----
__global__ __launch_bounds__(256) void qknorm_kernel(float* __restrict__ qkv,
                                                     const float* __restrict__ nqg,
                                                     const float* __restrict__ nqb,
                                                     const float* __restrict__ nkg,
                                                     const float* __restrict__ nkb) {
    int wid = threadIdx.x >> 6, lane = threadIdx.x & 63;
    int row = blockIdx.x * 4 + wid;        // (b*1024 + l)*16 + head
    int head = row & 15;
    int bl = row >> 4;
    float* base = qkv + (size_t)bl * 3072 + head * 64 + lane;
    #pragma unroll
    for (int part = 0; part < 2; part++) {
        float* p = base + part * 1024;
        float v = *p;
        float s = v, sq = v * v;
        #pragma unroll
        for (int off = 32; off; off >>= 1) { s += __shfl_xor(s, off); sq += __shfl_xor(sq, off); }
        float mu = s * (1.f / 64.f);
        float var = sq * (1.f / 64.f) - mu * mu;
        float rs = rsqrtf(var + 1e-5f);
        const float* gg = part ? nkg : nqg;
        const float* bb = part ? nkb : nqb;
        *p = (v - mu) * rs * gg[lane] + bb[lane];
    }
}

// ---------------- K transpose: qkv K part -> kT[b][h][dd][l] ----------------
__global__ __launch_bounds__(256) void ktrans_kernel(const float* __restrict__ qkv,
                                                     float* __restrict__ kT) {
    __shared__ float t[64][65];
    int l0 = blockIdx.x * 64, head = blockIdx.y, b = blockIdx.z;
    for (int i = threadIdx.x; i < 4096; i += 256) {
        int lr = i >> 6, dd = i & 63;
        t[lr][dd] = qkv[((size_t)(b * 1024 + l0 + lr)) * 3072 + 1024 + head * 64 + dd];
    }
    __syncthreads();
    for (int i = threadIdx.x; i < 4096; i += 256) {
        int dd = i >> 6, lc = i & 63;
        kT[((size_t)((b * 16 + head) * 64 + dd)) * 1024 + l0 + lc] = t[lc][dd];
    }
}

// ---------------- attention: one block per (qtile of 8, head, b) -------------
#define QT 8
__global__ __launch_bounds__(256) void attn_kernel(const float* __restrict__ qkv,
                                                   const float* __restrict__ kT,
                                                   float* __restrict__ ob) {
    __shared__ float Sl[1024][8];   // [l][r] scores, later aliased as partials
    __shared__ float Qs[64][8];     // [dd][r], pre-scaled
    __shared__ float redm[4][8];
    __shared__ float invs[8];
    int tid = threadIdx.x;
    int b = blockIdx.z, head = blockIdx.y, q0 = blockIdx.x * QT;
    const float* qbase = qkv + ((size_t)b * 1024) * 3072 + head * 64;
    for (int i = tid; i < 512; i += 256) {
        int r = i >> 6, dd = i & 63;
        Qs[dd][r] = qbase[(size_t)(q0 + r) * 3072 + dd] * 0.125f;
    }
    __syncthreads();
    // ---- phase 1: S = (Q*scale) K^T ; each thread: 4 l-cols x 8 rows ----
    {
        const float* kcol = kT + ((size_t)((b * 16 + head) * 64)) * 1024 + tid;
        float acc[4][8];
        #pragma unroll
        for (int c = 0; c < 4; c++)
            #pragma unroll
            for (int r = 0; r < 8; r++) acc[c][r] = 0.f;
        for (int dd = 0; dd < 64; dd++) {
            float k0 = kcol[(size_t)dd * 1024];
            float k1 = kcol[(size_t)dd * 1024 + 256];
            float k2 = kcol[(size_t)dd * 1024 + 512];
            float k3 = kcol[(size_t)dd * 1024 + 768];
            float4 qa = *(const float4*)&Qs[dd][0];
            float4 qb = *(const float4*)&Qs[dd][4];
            acc[0][0] += k0 * qa.x; acc[0][1] += k0 * qa.y; acc[0][2] += k0 * qa.z; acc[0][3] += k0 * qa.w;
            acc[0][4] += k0 * qb.x; acc[0][5] += k0 * qb.y; acc[0][6] += k0 * qb.z; acc[0][7] += k0 * qb.w;
            acc[1][0] += k1 * qa.x; acc[1][1] += k1 * qa.y; acc[1][2] += k1 * qa.z; acc[1][3] += k1 * qa.w;
            acc[1][4] += k1 * qb.x; acc[1][5] += k1 * qb.y; acc[1][6] += k1 * qb.z; acc[1][7] += k1 * qb.w;
            acc[2][0] += k2 * qa.x; acc[2][1] += k2 * qa.y; acc[2][2] += k2 * qa.z; acc[2][3] += k2 * qa.w;
            acc[2][4] += k2 * qb.x; acc[2][5] += k2 * qb.y; acc[2][6] += k2 * qb.z; acc[2][7] += k2 * qb.w;
            acc[3][0] += k3 * qa.x; acc[3][1] += k3 * qa.y; acc[3][2] += k3 * qa.z; acc[3][3] += k3 * qa.w;
            acc[3][4] += k3 * qb.x; acc[3][5] += k3 * qb.y; acc[3][6] += k3 * qb.z; acc[3][7] += k3 * qb.w;
        }
        #pragma unroll
        for (int c = 0; c < 4; c++) {
            int l = tid + c * 256;
            *(float4*)&Sl[l][0] = make_float4(acc[c][0], acc[c][1], acc[c][2], acc[c][3]);
            *(float4*)&Sl[l][4] = make_float4(acc[c][4], acc[c][5], acc[c][6], acc[c][7]);
        }
    }
    __syncthreads();
    // ---- phase 2: softmax per row (lane -> (row, l-group)); defer 1/sum ----
    {
        int r = tid & 7, g = tid >> 3;       // g: 0..31
        int w = tid >> 6;
        float m = -1e30f;
        #pragma unroll 4
        for (int j = 0; j < 32; j++) m = fmaxf(m, Sl[g + j * 32][r]);
        m = fmaxf(m, __shfl_xor(m, 8));
        m = fmaxf(m, __shfl_xor(m, 16));
        m = fmaxf(m, __shfl_xor(m, 32));
        if ((tid & 63) < 8) redm[w][r] = m;
        __syncthreads();
        m = fmaxf(fmaxf(redm[0][r], redm[1][r]), fmaxf(redm[2][r], redm[3][r]));
        __syncthreads();
        float s = 0.f;
        #pragma unroll 4
        for (int j = 0; j < 32; j++) {
            int l = g + j * 32;
            float e = __expf(Sl[l][r] - m);
            Sl[l][r] = e;
            s += e;
        }
        s += __shfl_xor(s, 8); s += __shfl_xor(s, 16); s += __shfl_xor(s, 32);
        if ((tid & 63) < 8) redm[w][r] = s;
        __syncthreads();
        if (tid < 8) invs[tid] = 1.f / (redm[0][tid] + redm[1][tid] + redm[2][tid] + redm[3][tid]);
    }
    __syncthreads();
    // ---- phase 3: O = P V ; thread: 4 dd-cols x 8 rows, 64-l chunk ----
    {
        int dd4 = (tid & 15) * 4, chunk = tid >> 4;   // 16 chunks of 64 l
        const float* vbase = qkv + ((size_t)b * 1024) * 3072 + 2048 + head * 64 + dd4;
        float acc[8][4];
        #pragma unroll
        for (int r = 0; r < 8; r++)
            #pragma unroll
            for (int c = 0; c < 4; c++) acc[r][c] = 0.f;
        #pragma unroll 2
        for (int j = 0; j < 64; j++) {
            int l = chunk * 64 + j;
            float4 v = *(const float4*)(vbase + (size_t)l * 3072);
            float4 sa = *(const float4*)&Sl[l][0];
            float4 sb = *(const float4*)&Sl[l][4];
            acc[0][0] += sa.x * v.x; acc[0][1] += sa.x * v.y; acc[0][2] += sa.x * v.z; acc[0][3] += sa.x * v.w;
            acc[1][0] += sa.y * v.x; acc[1][1] += sa.y * v.y; acc[1][2] += sa.y * v.z; acc[1][3] += sa.y * v.w;
            acc[2][0] += sa.z * v.x; acc[2][1] += sa.z * v.y; acc[2][2] += sa.z * v.z; acc[2][3] += sa.z * v.w;
            acc[3][0] += sa.w * v.x; acc[3][1] += sa.w * v.y; acc[3][2] += sa.w * v.z; acc[3][3] += sa.w * v.w;
            acc[4][0] += sb.x * v.x; acc[4][1] += sb.x * v.y; acc[4][2] += sb.x * v.z; acc[4][3] += sb.x * v.w;
            acc[5][0] += sb.y * v.x; acc[5][1] += sb.y * v.y; acc[5][2] += sb.y * v.z; acc[5][3] += sb.y * v.w;
            acc[6][0] += sb.z * v.x; acc[6][1] += sb.z * v.y; acc[6][2] += sb.z * v.z; acc[6][3] += sb.z * v.w;
            acc[7][0] += sb.w * v.x; acc[7][1] += sb.w * v.y; acc[7][2] += sb.w * v.z; acc[7][3] += sb.w * v.w;
        }
        __syncthreads();                     // all S reads done
        float* part = &Sl[0][0];             // [chunk][r][dd] = 16*8*64 floats (32 KB)
        #pragma unroll
        for (int r = 0; r < 8; r++)
            *(float4*)&part[((size_t)chunk * 8 + r) * 64 + dd4] =
                make_float4(acc[r][0], acc[r][1], acc[r][2], acc[r][3]);
        __syncthreads();
        for (int o = tid; o < 512; o += 256) {
            int r = o >> 6, dd = o & 63;
            float s = 0.f;
            #pragma unroll
            for (int ch = 0; ch < 16; ch++) s += part[((size_t)ch * 8 + r) * 64 + dd];
            ob[((size_t)(b * 1024 + q0 + r)) * 1024 + head * 64 + dd] = s * invs[r];
        }
    }
}

// ---------------- tiled fp32 GEMM: C = act(A@B + bias) [+ C] ------------------
template <int BM, int BN, int TM, int TN, int ACT, bool ADDC>
__global__ __launch_bounds__(256) void gemm_kernel(const float* __restrict__ A,
                                                   const float* __restrict__ B,
                                                   const float* __restrict__ bias,
                                                   float* __restrict__ C,
                                                   int M, int N, int K) {
    const int BK = 16;
    __shared__ float As[BK][BM];
    __shared__ float Bs[BK][BN];
    int tid = threadIdx.x;
    int m0 = blockIdx.y * BM, n0 = blockIdx.x * BN;
    int tx = tid % (BN / TN), ty = tid / (BN / TN);
    float acc[TM][TN];
    #pragma unroll
    for (int i = 0; i < TM; i++)
        #pragma unroll
        for (int j = 0; j < TN; j++) acc[i][j] = 0.f;

    for (int k0 = 0; k0 < K; k0 += BK) {
        #pragma unroll
        for (int i = 0; i < BM * BK / 1024; i++) {
            int idx = tid + i * 256;
            int r = idx / (BK / 4), c4 = idx % (BK / 4);
            float4 a = *(const float4*)(A + (size_t)(m0 + r) * K + k0 + c4 * 4);
            As[c4 * 4 + 0][r] = a.x; As[c4 * 4 + 1][r] = a.y;
            As[c4 * 4 + 2][r] = a.z; As[c4 * 4 + 3][r] = a.w;
        }
        #pragma unroll
        for (int i = 0; i < BK * BN / 1024; i++) {
            int idx = tid + i * 256;
            int r = idx / (BN / 4), c4 = idx % (BN / 4);
            *(float4*)&Bs[r][c4 * 4] = *(const float4*)(B + (size_t)(k0 + r) * N + n0 + c4 * 4);
        }
        __syncthreads();
        #pragma unroll
        for (int k = 0; k < BK; k++) {
            float ar[TM], br[TN];
            #pragma unroll
            for (int i = 0; i < TM; i++) ar[i] = As[k][ty * TM + i];
            #pragma unroll
            for (int j = 0; j < TN; j++) br[j] = Bs[k][tx * TN + j];
            #pragma unroll
            for (int i = 0; i < TM; i++)
                #pragma unroll
                for (int j = 0; j < TN; j++) acc[i][j] += ar[i] * br[j];
        }
        __syncthreads();
    }
    #pragma unroll
    for (int i = 0; i < TM; i++) {
        int m = m0 + ty * TM + i;
        #pragma unroll
        for (int j = 0; j < TN; j++) {
            int n = n0 + tx * TN + j;
            float v = acc[i][j] + bias[n];
            if (ACT == 1) v = 0.5f * v * (1.f + erff(v * 0.70710678118654752f));
            if (ADDC) v += C[(size_t)m * N + n];
            C[(size_t)m * N + n] = v;
        }
    }
}

// ---------------- unpatchify ----------------
__global__ void unpatchify_kernel(const float* __restrict__ xf, float* __restrict__ img) {
    int idx = blockIdx.x * 256 + threadIdx.x;   // 2*64*64*64
    int x = idx & 63, y = (idx >> 6) & 63, ch = (idx >> 12) & 63, b = idx >> 18;
    int hh = y >> 1, ww = x >> 1, p = y & 1, q = x & 1;
    img[idx] = xf[((size_t)b * 1024 + hh * 32 + ww) * 256 + ch * 4 + p * 2 + q];
}

// ---------------- conv1: 64->16 ch, 3x3, pad 1, relu ----------------
__global__ void conv1_kernel(const float* __restrict__ img, const float* __restrict__ w,
                             const float* __restrict__ bias, float* __restrict__ out) {
    int idx = blockIdx.x * 256 + threadIdx.x;   // 2*16*64*64
    int x = idx & 63, y = (idx >> 6) & 63, oc = (idx >> 12) & 15, b = idx >> 16;
    const float* ib = img + (size_t)b * 64 * 64 * 64;
    float s = bias[oc];
    for (int ic = 0; ic < 64; ic++) {
        const float* ip = ib + ic * 4096;
        const float* wp = w + (oc * 64 + ic) * 9;
        #pragma unroll
        for (int ky = 0; ky < 3; ky++) {
            int yy = y + ky - 1;
            if (yy < 0 || yy > 63) continue;
            #pragma unroll
            for (int kx = 0; kx < 3; kx++) {
                int xx = x + kx - 1;
                if (xx < 0 || xx > 63) continue;
                s += ip[yy * 64 + xx] * wp[ky * 3 + kx];
            }
        }
    }
    out[idx] = fmaxf(s, 0.f);
}

// ---------------- conv2: 16->3 ch, 3x3, pad 1 ----------------
__global__ void conv2_kernel(const float* __restrict__ in, const float* __restrict__ w,
                             const float* __restrict__ bias, float* __restrict__ out) {
    int idx = blockIdx.x * 256 + threadIdx.x;   // 2*3*64*64 = 24576
    if (idx >= 24576) return;
    int x = idx & 63, y = (idx >> 6) & 63;
    int t = idx >> 12;
    int oc = t % 3, b = t / 3;
    const float* ib = in + (size_t)b * 16 * 4096;
    float s = bias[oc];
    for (int ic = 0; ic < 16; ic++) {
        const float* ip = ib + ic * 4096;
        const float* wp = w + (oc * 16 + ic) * 9;
        #pragma unroll
        for (int ky = 0; ky < 3; ky++) {
            int yy = y + ky - 1;
            if (yy < 0 || yy > 63) continue;
            #pragma unroll
            for (int kx = 0; kx < 3; kx++) {
                int xx = x + kx - 1;
                if (xx < 0 || xx > 63) continue;
                s += ip[yy * 64 + xx] * wp[ky * 3 + kx];
            }
        }
    }
    out[idx] = s;
}

// ---------------- launch ----------------
extern "C" void kernel_launch(void* const* d_in, const int* in_sizes, int n_in,
                              void* d_out, int out_size, void* d_ws, size_t ws_size,
                              hipStream_t stream) {
    const float* x_in   = (const float*)d_in[0];
    const float* qkv_w  = (const float*)d_in[1];
    const float* qkv_b  = (const float*)d_in[2];
    const float* proj_w = (const float*)d_in[3];
    const float* proj_b = (const float*)d_in[4];
    const float* nq_g   = (const float*)d_in[5];
    const float* nq_b   = (const float*)d_in[6];
    const float* nk_g   = (const float*)d_in[7];
    const float* nk_b   = (const float*)d_in[8];
    const float* n1_g   = (const float*)d_in[9];
    const float* n1_b   = (const float*)d_in[10];
    const float* n2_g   = (const float*)d_in[11];
    const float* n2_b   = (const float*)d_in[12];
    const float* fc1_w  = (const float*)d_in[13];
    const float* fc1_b  = (const float*)d_in[14];
    const float* fc2_w  = (const float*)d_in[15];
    const float* fc2_b  = (const float*)d_in[16];
    const float* fin_w  = (const float*)d_in[17];
    const float* fin_b  = (const float*)d_in[18];
    const float* c1_w   = (const float*)d_in[19];
    const float* c1_b   = (const float*)d_in[20];
    const float* c2_w   = (const float*)d_in[21];
    const float* c2_b   = (const float*)d_in[22];
    float* out = (float*)d_out;

    char* w = (char*)d_ws;
    float* xb  = (float*)w; w += (size_t)2 * 1024 * 1024 * 4;      // residual stream
    float* hn  = (float*)w; w += (size_t)2 * 1024 * 1024 * 4;      // LN out
    float* qkv = (float*)w; w += (size_t)2 * 1024 * 3072 * 4;
    float* ob  = (float*)w; w += (size_t)2 * 1024 * 1024 * 4;      // attn out
    float* mh  = (float*)w; w += (size_t)2 * 1024 * 4096 * 4;      // mlp hidden
    float* xf  = (float*)w; w += (size_t)2 * 1024 * 256 * 4;
    float* img = (float*)w; w += (size_t)2 * 64 * 64 * 64 * 4;
    float* c1o = (float*)w; w += (size_t)2 * 16 * 64 * 64 * 4;
    float* kT  = (float*)w; w += (size_t)2 * 16 * 64 * 1024 * 4;   // K transposed

    posembed_kernel<<<8192, 256, 0, stream>>>(x_in, xb);

    for (int i = 0; i < 4; i++) {
        ln_kernel<<<2048, 256, 0, stream>>>(xb, hn, n1_g + i * 1024, n1_b + i * 1024, 1e-5f, 1);
        gemm_kernel<128, 128, 8, 8, 0, false><<<dim3(24, 16), 256, 0, stream>>>(
            hn, qkv_w + (size_t)i * 1024 * 3072, qkv_b + i * 3072, qkv, 2048, 3072, 1024);
        qknorm_kernel<<<8192, 256, 0, stream>>>(qkv, nq_g + i * 64, nq_b + i * 64,
                                                nk_g + i * 64, nk_b + i * 64);
        ktrans_kernel<<<dim3(16, 16, 2), 256, 0, stream>>>(qkv, kT);
        attn_kernel<<<dim3(128, 16, 2), 256, 0, stream>>>(qkv, kT, ob);
        gemm_kernel<128, 64, 8, 4, 0, true><<<dim3(16, 16), 256, 0, stream>>>(
            ob, proj_w + (size_t)i * 1024 * 1024, proj_b + i * 1024, xb, 2048, 1024, 1024);
        ln_kernel<<<2048, 256, 0, stream>>>(xb, hn, n2_g + i * 1024, n2_b + i * 1024, 1e-5f, 1);
        gemm_kernel<128, 128, 8, 8, 1, false><<<dim3(32, 16), 256, 0, stream>>>(
            hn, fc1_w + (size_t)i * 1024 * 4096, fc1_b + i * 4096, mh, 2048, 4096, 1024);
        gemm_kernel<128, 64, 8, 4, 0, true><<<dim3(16, 16), 256, 0, stream>>>(
            mh, fc2_w + (size_t)i * 4096 * 1024, fc2_b + i * 1024, xb, 2048, 1024, 4096);
    }

    ln_kernel<<<2048, 256, 0, stream>>>(xb, hn, nullptr, nullptr, 1e-6f, 0);
    gemm_kernel<128, 64, 8, 4, 0, false><<<dim3(4, 16), 256, 0, stream>>>(
        hn, fin_w, fin_b, xf, 2048, 256, 1024);
    unpatchify_kernel<<<2048, 256, 0, stream>>>(xf, img);
    conv1_kernel<<<512, 256, 0, stream>>>(img, c1_w, c1_b, c1o);
    conv2_kernel<<<96, 256, 0, stream>>>(c1o, c2_w, c2_b, out);
}

// Round 3
// 1869.116 us; speedup vs baseline: 4.6449x; 2.4829x over previous
//
#include <hip/hip_runtime.h>
#include <hip/hip_bf16.h>
#include <math.h>

typedef float floatx4 __attribute__((ext_vector_type(4)));
typedef short bf16x8 __attribute__((ext_vector_type(8)));   // 8 bf16 in 4 VGPRs

__device__ __forceinline__ unsigned short f2bf(float x) {
    union { float f; unsigned int u; } v; v.f = x;
    unsigned int r = v.u + 0x7fffu + ((v.u >> 16) & 1u);    // RNE
    return (unsigned short)(r >> 16);
}

// CK-proven pattern: generic->AS casts via uintptr_t (LDS flat addr low 32 bits = LDS offset)
__device__ __forceinline__ void load_lds16(const void* g, void* l) {
    __builtin_amdgcn_global_load_lds(
        (const __attribute__((address_space(1))) unsigned int*)(uintptr_t)g,
        (__attribute__((address_space(3))) unsigned int*)(uintptr_t)l, 16, 0, 0);
}

// ---------------- pos embed + input add ----------------
__global__ void posembed_kernel(const float* __restrict__ xin, float* __restrict__ xb) {
    int idx = blockIdx.x * 256 + threadIdx.x;     // 2*1024*1024
    int c = idx & 1023;
    int n = (idx >> 10) & 1023;
    int pos = (c < 512) ? (n & 31) : (n >> 5);
    int cc = c & 511;
    int k = cc & 255;
    double om = exp(-(double)k * (9.210340371976184 / 256.0));
    double arg = (double)pos * om;
    float e = (float)((cc < 256) ? sin(arg) : cos(arg));
    xb[idx] = xin[idx] + e;
}

// ---------------- layernorm over C=1024, bf16 output ----------------
__global__ __launch_bounds__(256) void ln_kernel(const float* __restrict__ X,
                                                 unsigned short* __restrict__ Y,
                                                 const float* __restrict__ g,
                                                 const float* __restrict__ b,
                                                 float eps, int affine) {
    int row = blockIdx.x;
    const float4* xr = (const float4*)(X + (size_t)row * 1024);
    float4 x = xr[threadIdx.x];
    float s = x.x + x.y + x.z + x.w;
    float sq = x.x * x.x + x.y * x.y + x.z * x.z + x.w * x.w;
    __shared__ float red[8];
    #pragma unroll
    for (int off = 32; off; off >>= 1) { s += __shfl_xor(s, off); sq += __shfl_xor(sq, off); }
    int wid = threadIdx.x >> 6, lane = threadIdx.x & 63;
    if (!lane) { red[wid] = s; red[wid + 4] = sq; }
    __syncthreads();
    s = red[0] + red[1] + red[2] + red[3];
    sq = red[4] + red[5] + red[6] + red[7];
    float mu = s * (1.f / 1024.f);
    float var = sq * (1.f / 1024.f) - mu * mu;
    float rs = rsqrtf(var + eps);
    int c = threadIdx.x * 4;
    float4 y;
    if (affine) {
        y.x = (x.x - mu) * rs * g[c + 0] + b[c + 0];
        y.y = (x.y - mu) * rs * g[c + 1] + b[c + 1];
        y.z = (x.z - mu) * rs * g[c + 2] + b[c + 2];
        y.w = (x.w - mu) * rs * g[c + 3] + b[c + 3];
    } else {
        y.x = (x.x - mu) * rs; y.y = (x.y - mu) * rs;
        y.z = (x.z - mu) * rs; y.w = (x.w - mu) * rs;
    }
    ushort4 o;
    o.x = f2bf(y.x); o.y = f2bf(y.y); o.z = f2bf(y.z); o.w = f2bf(y.w);
    *(ushort4*)(Y + (size_t)row * 1024 + c) = o;
}

// ---------------- qk-norm (LN over d=64, per (b,l,head)) ----
__global__ __launch_bounds__(256) void qknorm_kernel(float* __restrict__ qkv,
                                                     const float* __restrict__ nqg,
                                                     const float* __restrict__ nqb,
                                                     const float* __restrict__ nkg,
                                                     const float* __restrict__ nkb) {
    int wid = threadIdx.x >> 6, lane = threadIdx.x & 63;
    int row = blockIdx.x * 4 + wid;
    int head = row & 15;
    int bl = row >> 4;
    float* base = qkv + (size_t)bl * 3072 + head * 64 + lane;
    #pragma unroll
    for (int part = 0; part < 2; part++) {
        float* p = base + part * 1024;
        float v = *p;
        float s = v, sq = v * v;
        #pragma unroll
        for (int off = 32; off; off >>= 1) { s += __shfl_xor(s, off); sq += __shfl_xor(sq, off); }
        float mu = s * (1.f / 64.f);
        float var = sq * (1.f / 64.f) - mu * mu;
        float rs = rsqrtf(var + 1e-5f);
        const float* gg = part ? nkg : nqg;
        const float* bb = part ? nkb : nqb;
        *p = (v - mu) * rs * gg[lane] + bb[lane];
    }
}

// ---------------- K transpose: qkv K part -> kT[b][h][dd][l] ----------------
__global__ __launch_bounds__(256) void ktrans_kernel(const float* __restrict__ qkv,
                                                     float* __restrict__ kT) {
    __shared__ float t[64][65];
    int l0 = blockIdx.x * 64, head = blockIdx.y, b = blockIdx.z;
    for (int i = threadIdx.x; i < 4096; i += 256) {
        int lr = i >> 6, dd = i & 63;
        t[lr][dd] = qkv[((size_t)(b * 1024 + l0 + lr)) * 3072 + 1024 + head * 64 + dd];
    }
    __syncthreads();
    for (int i = threadIdx.x; i < 4096; i += 256) {
        int dd = i >> 6, lc = i & 63;
        kT[((size_t)((b * 16 + head) * 64 + dd)) * 1024 + l0 + lc] = t[lc][dd];
    }
}

// ---------------- attention: one block per (qtile of 8, head, b); bf16 out ---
#define QT 8
__global__ __launch_bounds__(256) void attn_kernel(const float* __restrict__ qkv,
                                                   const float* __restrict__ kT,
                                                   unsigned short* __restrict__ ob) {
    __shared__ float Sl[1024][8];
    __shared__ float Qs[64][8];
    __shared__ float redm[4][8];
    __shared__ float invs[8];
    int tid = threadIdx.x;
    int b = blockIdx.z, head = blockIdx.y, q0 = blockIdx.x * QT;
    const float* qbase = qkv + ((size_t)b * 1024) * 3072 + head * 64;
    for (int i = tid; i < 512; i += 256) {
        int r = i >> 6, dd = i & 63;
        Qs[dd][r] = qbase[(size_t)(q0 + r) * 3072 + dd] * 0.125f;
    }
    __syncthreads();
    {
        const float* kcol = kT + ((size_t)((b * 16 + head) * 64)) * 1024 + tid;
        float acc[4][8];
        #pragma unroll
        for (int c = 0; c < 4; c++)
            #pragma unroll
            for (int r = 0; r < 8; r++) acc[c][r] = 0.f;
        for (int dd = 0; dd < 64; dd++) {
            float k0 = kcol[(size_t)dd * 1024];
            float k1 = kcol[(size_t)dd * 1024 + 256];
            float k2 = kcol[(size_t)dd * 1024 + 512];
            float k3 = kcol[(size_t)dd * 1024 + 768];
            float4 qa = *(const float4*)&Qs[dd][0];
            float4 qb = *(const float4*)&Qs[dd][4];
            acc[0][0] += k0 * qa.x; acc[0][1] += k0 * qa.y; acc[0][2] += k0 * qa.z; acc[0][3] += k0 * qa.w;
            acc[0][4] += k0 * qb.x; acc[0][5] += k0 * qb.y; acc[0][6] += k0 * qb.z; acc[0][7] += k0 * qb.w;
            acc[1][0] += k1 * qa.x; acc[1][1] += k1 * qa.y; acc[1][2] += k1 * qa.z; acc[1][3] += k1 * qa.w;
            acc[1][4] += k1 * qb.x; acc[1][5] += k1 * qb.y; acc[1][6] += k1 * qb.z; acc[1][7] += k1 * qb.w;
            acc[2][0] += k2 * qa.x; acc[2][1] += k2 * qa.y; acc[2][2] += k2 * qa.z; acc[2][3] += k2 * qa.w;
            acc[2][4] += k2 * qb.x; acc[2][5] += k2 * qb.y; acc[2][6] += k2 * qb.z; acc[2][7] += k2 * qb.w;
            acc[3][0] += k3 * qa.x; acc[3][1] += k3 * qa.y; acc[3][2] += k3 * qa.z; acc[3][3] += k3 * qa.w;
            acc[3][4] += k3 * qb.x; acc[3][5] += k3 * qb.y; acc[3][6] += k3 * qb.z; acc[3][7] += k3 * qb.w;
        }
        #pragma unroll
        for (int c = 0; c < 4; c++) {
            int l = tid + c * 256;
            *(float4*)&Sl[l][0] = make_float4(acc[c][0], acc[c][1], acc[c][2], acc[c][3]);
            *(float4*)&Sl[l][4] = make_float4(acc[c][4], acc[c][5], acc[c][6], acc[c][7]);
        }
    }
    __syncthreads();
    {
        int r = tid & 7, g = tid >> 3;
        int w = tid >> 6;
        float m = -1e30f;
        #pragma unroll 4
        for (int j = 0; j < 32; j++) m = fmaxf(m, Sl[g + j * 32][r]);
        m = fmaxf(m, __shfl_xor(m, 8));
        m = fmaxf(m, __shfl_xor(m, 16));
        m = fmaxf(m, __shfl_xor(m, 32));
        if ((tid & 63) < 8) redm[w][r] = m;
        __syncthreads();
        m = fmaxf(fmaxf(redm[0][r], redm[1][r]), fmaxf(redm[2][r], redm[3][r]));
        __syncthreads();
        float s = 0.f;
        #pragma unroll 4
        for (int j = 0; j < 32; j++) {
            int l = g + j * 32;
            float e = __expf(Sl[l][r] - m);
            Sl[l][r] = e;
            s += e;
        }
        s += __shfl_xor(s, 8); s += __shfl_xor(s, 16); s += __shfl_xor(s, 32);
        if ((tid & 63) < 8) redm[w][r] = s;
        __syncthreads();
        if (tid < 8) invs[tid] = 1.f / (redm[0][tid] + redm[1][tid] + redm[2][tid] + redm[3][tid]);
    }
    __syncthreads();
    {
        int dd4 = (tid & 15) * 4, chunk = tid >> 4;
        const float* vbase = qkv + ((size_t)b * 1024) * 3072 + 2048 + head * 64 + dd4;
        float acc[8][4];
        #pragma unroll
        for (int r = 0; r < 8; r++)
            #pragma unroll
            for (int c = 0; c < 4; c++) acc[r][c] = 0.f;
        #pragma unroll 2
        for (int j = 0; j < 64; j++) {
            int l = chunk * 64 + j;
            float4 v = *(const float4*)(vbase + (size_t)l * 3072);
            float4 sa = *(const float4*)&Sl[l][0];
            float4 sb = *(const float4*)&Sl[l][4];
            acc[0][0] += sa.x * v.x; acc[0][1] += sa.x * v.y; acc[0][2] += sa.x * v.z; acc[0][3] += sa.x * v.w;
            acc[1][0] += sa.y * v.x; acc[1][1] += sa.y * v.y; acc[1][2] += sa.y * v.z; acc[1][3] += sa.y * v.w;
            acc[2][0] += sa.z * v.x; acc[2][1] += sa.z * v.y; acc[2][2] += sa.z * v.z; acc[2][3] += sa.z * v.w;
            acc[3][0] += sa.w * v.x; acc[3][1] += sa.w * v.y; acc[3][2] += sa.w * v.z; acc[3][3] += sa.w * v.w;
            acc[4][0] += sb.x * v.x; acc[4][1] += sb.x * v.y; acc[4][2] += sb.x * v.z; acc[4][3] += sb.x * v.w;
            acc[5][0] += sb.y * v.x; acc[5][1] += sb.y * v.y; acc[5][2] += sb.y * v.z; acc[5][3] += sb.y * v.w;
            acc[6][0] += sb.z * v.x; acc[6][1] += sb.z * v.y; acc[6][2] += sb.z * v.z; acc[6][3] += sb.z * v.w;
            acc[7][0] += sb.w * v.x; acc[7][1] += sb.w * v.y; acc[7][2] += sb.w * v.z; acc[7][3] += sb.w * v.w;
        }
        __syncthreads();
        float* part = &Sl[0][0];
        #pragma unroll
        for (int r = 0; r < 8; r++)
            *(float4*)&part[((size_t)chunk * 8 + r) * 64 + dd4] =
                make_float4(acc[r][0], acc[r][1], acc[r][2], acc[r][3]);
        __syncthreads();
        for (int o = tid; o < 512; o += 256) {
            int r = o >> 6, dd = o & 63;
            float s = 0.f;
            #pragma unroll
            for (int ch = 0; ch < 16; ch++) s += part[((size_t)ch * 8 + r) * 64 + dd];
            ob[((size_t)(b * 1024 + q0 + r)) * 1024 + head * 64 + dd] = f2bf(s * invs[r]);
        }
    }
}

// ------- weight transpose + bf16 convert: in fp32 [K][N] -> out bf16 [N][K] -------
__global__ __launch_bounds__(256) void wtrans_kernel(const float* __restrict__ in,
                                                     unsigned short* __restrict__ out,
                                                     int K, int N) {
    __shared__ float t[64][65];
    int n0 = blockIdx.x * 64, k0 = blockIdx.y * 64;
    for (int i = threadIdx.x; i < 4096; i += 256) {
        int kr = i >> 6, nc = i & 63;
        t[kr][nc] = in[(size_t)(k0 + kr) * N + n0 + nc];
    }
    __syncthreads();
    for (int i = threadIdx.x; i < 4096; i += 256) {
        int nr = i >> 6, kc = i & 63;
        out[(size_t)(n0 + nr) * K + k0 + kc] = f2bf(t[kc][nr]);
    }
}

// ------- bf16 MFMA GEMM: C = act(A@B + bias)[+C]; A[M][K] bf16, Bt[N][K] bf16 -----
// 128x128 tile, BK=32, 4 waves in 2x2, each wave 4x4 of mfma_f32_16x16x32_bf16.
template <int ACT, bool ADDC, bool OUTBF16>
__global__ __launch_bounds__(256) void gemm_bf16(const unsigned short* __restrict__ A,
                                                 const unsigned short* __restrict__ Bt,
                                                 const float* __restrict__ bias,
                                                 float* __restrict__ Cf,
                                                 unsigned short* __restrict__ Cb,
                                                 int M, int N, int K) {
    __shared__ short As[128 * 32];
    __shared__ short Bs[128 * 32];
    int tid = threadIdx.x;
    int lane = tid & 63, wave = tid >> 6;
    int wm = wave >> 1, wn = wave & 1;
    int ln16 = lane & 15, q = lane >> 4;
    int m0 = blockIdx.y * 128, n0 = blockIdx.x * 128;

    floatx4 acc[4][4];
    #pragma unroll
    for (int i = 0; i < 4; i++)
        #pragma unroll
        for (int j = 0; j < 4; j++) acc[i][j] = (floatx4){0.f, 0.f, 0.f, 0.f};

    int kSteps = K >> 5;
    for (int ks = 0; ks < kSteps; ks++) {
        int k0 = ks << 5;
        #pragma unroll
        for (int it = 0; it < 2; it++) {
            int i = tid + it * 256;
            int row = i >> 2, ch = (i & 3) * 8;
            load_lds16(A + (size_t)(m0 + row) * K + k0 + ch, &As[i * 8]);
            load_lds16(Bt + (size_t)(n0 + row) * K + k0 + ch, &Bs[i * 8]);
        }
        __syncthreads();
        bf16x8 af[4], bf[4];
        #pragma unroll
        for (int mi = 0; mi < 4; mi++)
            af[mi] = *(const bf16x8*)&As[(wm * 64 + mi * 16 + ln16) * 32 + q * 8];
        #pragma unroll
        for (int ni = 0; ni < 4; ni++)
            bf[ni] = *(const bf16x8*)&Bs[(wn * 64 + ni * 16 + ln16) * 32 + q * 8];
        #pragma unroll
        for (int mi = 0; mi < 4; mi++)
            #pragma unroll
            for (int ni = 0; ni < 4; ni++)
                acc[mi][ni] = __builtin_amdgcn_mfma_f32_16x16x32_bf16(af[mi], bf[ni], acc[mi][ni], 0, 0, 0);
        __syncthreads();
    }

    int q4 = q * 4;
    #pragma unroll
    for (int ni = 0; ni < 4; ni++) {
        int col = n0 + wn * 64 + ni * 16 + ln16;
        float bv = bias[col];
        #pragma unroll
        for (int mi = 0; mi < 4; mi++) {
            #pragma unroll
            for (int r = 0; r < 4; r++) {
                int row = m0 + wm * 64 + mi * 16 + q4 + r;
                size_t off = (size_t)row * N + col;
                float v = acc[mi][ni][r] + bv;
                if (ACT == 1) v = 0.5f * v * (1.f + erff(v * 0.70710678118654752f));
                if (ADDC) v += Cf[off];
                if (OUTBF16) Cb[off] = f2bf(v);
                else Cf[off] = v;
            }
        }
    }
}

// ---------------- unpatchify ----------------
__global__ void unpatchify_kernel(const float* __restrict__ xf, float* __restrict__ img) {
    int idx = blockIdx.x * 256 + threadIdx.x;
    int x = idx & 63, y = (idx >> 6) & 63, ch = (idx >> 12) & 63, b = idx >> 18;
    int hh = y >> 1, ww = x >> 1, p = y & 1, qq = x & 1;
    img[idx] = xf[((size_t)b * 1024 + hh * 32 + ww) * 256 + ch * 4 + p * 2 + qq];
}

// ---------------- conv1: 64->16 ch, 3x3, pad 1, relu ----------------
__global__ void conv1_kernel(const float* __restrict__ img, const float* __restrict__ w,
                             const float* __restrict__ bias, float* __restrict__ out) {
    int idx = blockIdx.x * 256 + threadIdx.x;
    int x = idx & 63, y = (idx >> 6) & 63, oc = (idx >> 12) & 15, b = idx >> 16;
    const float* ib = img + (size_t)b * 64 * 64 * 64;
    float s = bias[oc];
    for (int ic = 0; ic < 64; ic++) {
        const float* ip = ib + ic * 4096;
        const float* wp = w + (oc * 64 + ic) * 9;
        #pragma unroll
        for (int ky = 0; ky < 3; ky++) {
            int yy = y + ky - 1;
            if (yy < 0 || yy > 63) continue;
            #pragma unroll
            for (int kx = 0; kx < 3; kx++) {
                int xx = x + kx - 1;
                if (xx < 0 || xx > 63) continue;
                s += ip[yy * 64 + xx] * wp[ky * 3 + kx];
            }
        }
    }
    out[idx] = fmaxf(s, 0.f);
}

// ---------------- conv2: 16->3 ch, 3x3, pad 1 ----------------
__global__ void conv2_kernel(const float* __restrict__ in, const float* __restrict__ w,
                             const float* __restrict__ bias, float* __restrict__ out) {
    int idx = blockIdx.x * 256 + threadIdx.x;
    if (idx >= 24576) return;
    int x = idx & 63, y = (idx >> 6) & 63;
    int t = idx >> 12;
    int oc = t % 3, b = t / 3;
    const float* ib = in + (size_t)b * 16 * 4096;
    float s = bias[oc];
    for (int ic = 0; ic < 16; ic++) {
        const float* ip = ib + ic * 4096;
        const float* wp = w + (oc * 16 + ic) * 9;
        #pragma unroll
        for (int ky = 0; ky < 3; ky++) {
            int yy = y + ky - 1;
            if (yy < 0 || yy > 63) continue;
            #pragma unroll
            for (int kx = 0; kx < 3; kx++) {
                int xx = x + kx - 1;
                if (xx < 0 || xx > 63) continue;
                s += ip[yy * 64 + xx] * wp[ky * 3 + kx];
            }
        }
    }
    out[idx] = s;
}

// ---------------- launch ----------------
extern "C" void kernel_launch(void* const* d_in, const int* in_sizes, int n_in,
                              void* d_out, int out_size, void* d_ws, size_t ws_size,
                              hipStream_t stream) {
    const float* x_in   = (const float*)d_in[0];
    const float* qkv_w  = (const float*)d_in[1];
    const float* qkv_b  = (const float*)d_in[2];
    const float* proj_w = (const float*)d_in[3];
    const float* proj_b = (const float*)d_in[4];
    const float* nq_g   = (const float*)d_in[5];
    const float* nq_b   = (const float*)d_in[6];
    const float* nk_g   = (const float*)d_in[7];
    const float* nk_b   = (const float*)d_in[8];
    const float* n1_g   = (const float*)d_in[9];
    const float* n1_b   = (const float*)d_in[10];
    const float* n2_g   = (const float*)d_in[11];
    const float* n2_b   = (const float*)d_in[12];
    const float* fc1_w  = (const float*)d_in[13];
    const float* fc1_b  = (const float*)d_in[14];
    const float* fc2_w  = (const float*)d_in[15];
    const float* fc2_b  = (const float*)d_in[16];
    const float* fin_w  = (const float*)d_in[17];
    const float* fin_b  = (const float*)d_in[18];
    const float* c1_w   = (const float*)d_in[19];
    const float* c1_b   = (const float*)d_in[20];
    const float* c2_w   = (const float*)d_in[21];
    const float* c2_b   = (const float*)d_in[22];
    float* out = (float*)d_out;

    char* w = (char*)d_ws;
    float* xb           = (float*)w;          w += (size_t)2 * 1024 * 1024 * 4;   // residual fp32
    unsigned short* hnb = (unsigned short*)w; w += (size_t)2 * 1024 * 1024 * 2;   // LN out bf16
    float* qkv          = (float*)w;          w += (size_t)2 * 1024 * 3072 * 4;   // fp32
    unsigned short* obb = (unsigned short*)w; w += (size_t)2 * 1024 * 1024 * 2;   // attn out bf16
    unsigned short* mhb = (unsigned short*)w; w += (size_t)2 * 1024 * 4096 * 2;   // mlp hidden bf16
    float* xf           = (float*)w;          w += (size_t)2 * 1024 * 256 * 4;
    float* img          = (float*)w;          w += (size_t)2 * 64 * 64 * 64 * 4;
    float* c1o          = (float*)w;          w += (size_t)2 * 16 * 64 * 64 * 4;
    float* kT           = (float*)w;          w += (size_t)2 * 16 * 64 * 1024 * 4;
    unsigned short* wq  = (unsigned short*)w; w += (size_t)1024 * 3072 * 2;       // per-block bf16 B^T
    unsigned short* wp  = (unsigned short*)w; w += (size_t)1024 * 1024 * 2;
    unsigned short* w1  = (unsigned short*)w; w += (size_t)1024 * 4096 * 2;
    unsigned short* w2  = (unsigned short*)w; w += (size_t)4096 * 1024 * 2;
    unsigned short* wfin= (unsigned short*)w; w += (size_t)1024 * 256 * 2;

    posembed_kernel<<<8192, 256, 0, stream>>>(x_in, xb);

    for (int i = 0; i < 4; i++) {
        wtrans_kernel<<<dim3(48, 16), 256, 0, stream>>>(qkv_w + (size_t)i * 1024 * 3072, wq, 1024, 3072);
        wtrans_kernel<<<dim3(16, 16), 256, 0, stream>>>(proj_w + (size_t)i * 1024 * 1024, wp, 1024, 1024);
        wtrans_kernel<<<dim3(64, 16), 256, 0, stream>>>(fc1_w + (size_t)i * 1024 * 4096, w1, 1024, 4096);
        wtrans_kernel<<<dim3(16, 64), 256, 0, stream>>>(fc2_w + (size_t)i * 4096 * 1024, w2, 4096, 1024);

        ln_kernel<<<2048, 256, 0, stream>>>(xb, hnb, n1_g + i * 1024, n1_b + i * 1024, 1e-5f, 1);
        gemm_bf16<0, false, false><<<dim3(24, 16), 256, 0, stream>>>(
            hnb, wq, qkv_b + i * 3072, qkv, nullptr, 2048, 3072, 1024);
        qknorm_kernel<<<8192, 256, 0, stream>>>(qkv, nq_g + i * 64, nq_b + i * 64,
                                                nk_g + i * 64, nk_b + i * 64);
        ktrans_kernel<<<dim3(16, 16, 2), 256, 0, stream>>>(qkv, kT);
        attn_kernel<<<dim3(128, 16, 2), 256, 0, stream>>>(qkv, kT, obb);
        gemm_bf16<0, true, false><<<dim3(8, 16), 256, 0, stream>>>(
            obb, wp, proj_b + i * 1024, xb, nullptr, 2048, 1024, 1024);
        ln_kernel<<<2048, 256, 0, stream>>>(xb, hnb, n2_g + i * 1024, n2_b + i * 1024, 1e-5f, 1);
        gemm_bf16<1, false, true><<<dim3(32, 16), 256, 0, stream>>>(
            hnb, w1, fc1_b + i * 4096, nullptr, mhb, 2048, 4096, 1024);
        gemm_bf16<0, true, false><<<dim3(8, 16), 256, 0, stream>>>(
            mhb, w2, fc2_b + i * 1024, xb, nullptr, 2048, 1024, 4096);
    }

    wtrans_kernel<<<dim3(4, 16), 256, 0, stream>>>(fin_w, wfin, 1024, 256);
    ln_kernel<<<2048, 256, 0, stream>>>(xb, hnb, nullptr, nullptr, 1e-6f, 0);
    gemm_bf16<0, false, false><<<dim3(2, 16), 256, 0, stream>>>(
        hnb, wfin, fin_b, xf, nullptr, 2048, 256, 1024);
    unpatchify_kernel<<<2048, 256, 0, stream>>>(xf, img);
    conv1_kernel<<<512, 256, 0, stream>>>(img, c1_w, c1_b, c1o);
    conv2_kernel<<<96, 256, 0, stream>>>(c1o, c2_w, c2_b, out);
}

// Round 4
// 1331.298 us; speedup vs baseline: 6.5213x; 1.4040x over previous
//
#include <hip/hip_runtime.h>
#include <hip/hip_bf16.h>
#include <math.h>

typedef float floatx4 __attribute__((ext_vector_type(4)));
typedef short bf16x8 __attribute__((ext_vector_type(8)));   // 8 bf16 in 4 VGPRs

__device__ __forceinline__ unsigned short f2bf(float x) {
    union { float f; unsigned int u; } v; v.f = x;
    unsigned int r = v.u + 0x7fffu + ((v.u >> 16) & 1u);    // RNE
    return (unsigned short)(r >> 16);
}

__device__ __forceinline__ void load_lds16(const void* g, void* l) {
    __builtin_amdgcn_global_load_lds(
        (const __attribute__((address_space(1))) unsigned int*)(uintptr_t)g,
        (__attribute__((address_space(3))) unsigned int*)(uintptr_t)l, 16, 0, 0);
}

// ---------------- pos embed + input add ----------------
__global__ void posembed_kernel(const float* __restrict__ xin, float* __restrict__ xb) {
    int idx = blockIdx.x * 256 + threadIdx.x;     // 2*1024*1024
    int c = idx & 1023;
    int n = (idx >> 10) & 1023;
    int pos = (c < 512) ? (n & 31) : (n >> 5);
    int cc = c & 511;
    int k = cc & 255;
    double om = exp(-(double)k * (9.210340371976184 / 256.0));
    double arg = (double)pos * om;
    float e = (float)((cc < 256) ? sin(arg) : cos(arg));
    xb[idx] = xin[idx] + e;
}

// ---------------- layernorm over C=1024, bf16 output ----------------
__global__ __launch_bounds__(256) void ln_kernel(const float* __restrict__ X,
                                                 unsigned short* __restrict__ Y,
                                                 const float* __restrict__ g,
                                                 const float* __restrict__ b,
                                                 float eps, int affine) {
    int row = blockIdx.x;
    const float4* xr = (const float4*)(X + (size_t)row * 1024);
    float4 x = xr[threadIdx.x];
    float s = x.x + x.y + x.z + x.w;
    float sq = x.x * x.x + x.y * x.y + x.z * x.z + x.w * x.w;
    __shared__ float red[8];
    #pragma unroll
    for (int off = 32; off; off >>= 1) { s += __shfl_xor(s, off); sq += __shfl_xor(sq, off); }
    int wid = threadIdx.x >> 6, lane = threadIdx.x & 63;
    if (!lane) { red[wid] = s; red[wid + 4] = sq; }
    __syncthreads();
    s = red[0] + red[1] + red[2] + red[3];
    sq = red[4] + red[5] + red[6] + red[7];
    float mu = s * (1.f / 1024.f);
    float var = sq * (1.f / 1024.f) - mu * mu;
    float rs = rsqrtf(var + eps);
    int c = threadIdx.x * 4;
    float4 y;
    if (affine) {
        y.x = (x.x - mu) * rs * g[c + 0] + b[c + 0];
        y.y = (x.y - mu) * rs * g[c + 1] + b[c + 1];
        y.z = (x.z - mu) * rs * g[c + 2] + b[c + 2];
        y.w = (x.w - mu) * rs * g[c + 3] + b[c + 3];
    } else {
        y.x = (x.x - mu) * rs; y.y = (x.y - mu) * rs;
        y.z = (x.z - mu) * rs; y.w = (x.w - mu) * rs;
    }
    ushort4 o;
    o.x = f2bf(y.x); o.y = f2bf(y.y); o.z = f2bf(y.z); o.w = f2bf(y.w);
    *(ushort4*)(Y + (size_t)row * 1024 + c) = o;
}

// ---- qk-norm: LN over d=64 per (b,l,head); writes bf16 Qb (x0.125) and Kb ----
__global__ __launch_bounds__(256) void qknorm_kernel(const float* __restrict__ qkv,
                                                     const float* __restrict__ nqg,
                                                     const float* __restrict__ nqb,
                                                     const float* __restrict__ nkg,
                                                     const float* __restrict__ nkb,
                                                     unsigned short* __restrict__ Qb,
                                                     unsigned short* __restrict__ Kb) {
    int wid = threadIdx.x >> 6, lane = threadIdx.x & 63;
    int row = blockIdx.x * 4 + wid;        // (b*1024+l)*16 + head
    int head = row & 15;
    int bl = row >> 4;
    const float* base = qkv + (size_t)bl * 3072 + head * 64 + lane;
    #pragma unroll
    for (int part = 0; part < 2; part++) {
        float v = base[part * 1024];
        float s = v, sq = v * v;
        #pragma unroll
        for (int off = 32; off; off >>= 1) { s += __shfl_xor(s, off); sq += __shfl_xor(sq, off); }
        float mu = s * (1.f / 64.f);
        float var = sq * (1.f / 64.f) - mu * mu;
        float rs = rsqrtf(var + 1e-5f);
        const float* gg = part ? nkg : nqg;
        const float* bb = part ? nkb : nqb;
        float y = (v - mu) * rs * gg[lane] + bb[lane];
        if (part == 0) Qb[(size_t)bl * 1024 + head * 64 + lane] = f2bf(y * 0.125f);
        else           Kb[(size_t)bl * 1024 + head * 64 + lane] = f2bf(y);
    }
}

// ---- V transpose: qkv V part fp32 -> Vt bf16 [b][h][d][l] ----
__global__ __launch_bounds__(256) void vtrans_kernel(const float* __restrict__ qkv,
                                                     unsigned short* __restrict__ Vt) {
    __shared__ float t[64][65];
    int l0 = blockIdx.x * 64, head = blockIdx.y, b = blockIdx.z;
    for (int i = threadIdx.x; i < 4096; i += 256) {
        int lr = i >> 6, dd = i & 63;
        t[lr][dd] = qkv[((size_t)(b * 1024 + l0 + lr)) * 3072 + 2048 + head * 64 + dd];
    }
    __syncthreads();
    for (int i = threadIdx.x; i < 4096; i += 256) {
        int dd = i >> 6, lc = i & 63;
        Vt[((size_t)((b * 16 + head) * 64 + dd)) * 1024 + l0 + lc] = f2bf(t[lc][dd]);
    }
}

// ---- MFMA flash attention: block = (64 q-rows, head, b); 4 waves x 16 rows ----
__global__ __launch_bounds__(256) void attn_mfma(const unsigned short* __restrict__ Qb,
                                                 const unsigned short* __restrict__ Kb,
                                                 const unsigned short* __restrict__ Vt,
                                                 unsigned short* __restrict__ ob) {
    __shared__ short Ks[64 * 64];       // [l_local][d]
    __shared__ short Vs[64 * 64];       // [d][l_local]
    __shared__ short Pl[4][16 * 72];    // per-wave P tile, padded stride 72
    int tid = threadIdx.x;
    int lane = tid & 63, wave = tid >> 6;
    int ln16 = lane & 15, q = lane >> 4;
    int b = blockIdx.z, h = blockIdx.y, q0 = blockIdx.x * 64;

    // Q A-frags (held in regs): row = q0 + wave*16 + ln16, k = s*32 + q*8
    const unsigned short* qrow = Qb + ((size_t)(b * 1024 + q0 + wave * 16 + ln16)) * 1024 + h * 64;
    bf16x8 qf0 = *(const bf16x8*)(qrow + q * 8);
    bf16x8 qf1 = *(const bf16x8*)(qrow + 32 + q * 8);

    floatx4 o[4];
    #pragma unroll
    for (int td = 0; td < 4; td++) o[td] = (floatx4){0.f, 0.f, 0.f, 0.f};
    float mrow[4] = {-1e30f, -1e30f, -1e30f, -1e30f};
    float lrow[4] = {0.f, 0.f, 0.f, 0.f};

    const unsigned short* kbase0 = Kb + ((size_t)(b * 1024)) * 1024 + h * 64;
    const unsigned short* vbase0 = Vt + ((size_t)((b * 16 + h) * 64)) * 1024;

    for (int ch = 0; ch < 16; ch++) {
        int l0 = ch * 64;
        __syncthreads();                    // protect prev iter's Ks/Vs reads
        #pragma unroll
        for (int it = 0; it < 2; it++) {
            int j = tid + it * 256;
            int row = j >> 3, g = j & 7;
            load_lds16(kbase0 + (size_t)(l0 + row) * 1024 + g * 8, &Ks[j * 8]);
            load_lds16(vbase0 + (size_t)row * 1024 + l0 + g * 8, &Vs[j * 8]);
        }
        __syncthreads();

        // S = Q K^T  (4 col-tiles of 16)
        floatx4 s[4];
        #pragma unroll
        for (int t = 0; t < 4; t++) {
            s[t] = (floatx4){0.f, 0.f, 0.f, 0.f};
            bf16x8 kf0 = *(const bf16x8*)&Ks[(t * 16 + ln16) * 64 + q * 8];
            bf16x8 kf1 = *(const bf16x8*)&Ks[(t * 16 + ln16) * 64 + 32 + q * 8];
            s[t] = __builtin_amdgcn_mfma_f32_16x16x32_bf16(qf0, kf0, s[t], 0, 0, 0);
            s[t] = __builtin_amdgcn_mfma_f32_16x16x32_bf16(qf1, kf1, s[t], 0, 0, 0);
        }
        // online softmax: lane holds cols (t*16+ln16), rows q*4+r
        float cm[4], rs[4], p[4][4];
        #pragma unroll
        for (int r = 0; r < 4; r++) {
            cm[r] = fmaxf(fmaxf(s[0][r], s[1][r]), fmaxf(s[2][r], s[3][r]));
        }
        #pragma unroll
        for (int off = 1; off < 16; off <<= 1) {
            #pragma unroll
            for (int r = 0; r < 4; r++) cm[r] = fmaxf(cm[r], __shfl_xor(cm[r], off));
        }
        #pragma unroll
        for (int r = 0; r < 4; r++) {
            float mnew = fmaxf(mrow[r], cm[r]);
            float alpha = __expf(mrow[r] - mnew);
            mrow[r] = mnew;
            rs[r] = 0.f;
            #pragma unroll
            for (int t = 0; t < 4; t++) {
                p[t][r] = __expf(s[t][r] - mnew);
                rs[r] += p[t][r];
            }
            lrow[r] *= alpha;
            #pragma unroll
            for (int td = 0; td < 4; td++) o[td][r] *= alpha;
        }
        #pragma unroll
        for (int off = 1; off < 16; off <<= 1) {
            #pragma unroll
            for (int r = 0; r < 4; r++) rs[r] += __shfl_xor(rs[r], off);
        }
        #pragma unroll
        for (int r = 0; r < 4; r++) lrow[r] += rs[r];

        // P -> LDS (row-major [m][72]) then A-frags
        short* pw = &Pl[wave][0];
        #pragma unroll
        for (int t = 0; t < 4; t++)
            #pragma unroll
            for (int r = 0; r < 4; r++)
                pw[(q * 4 + r) * 72 + t * 16 + ln16] = (short)f2bf(p[t][r]);
        __syncthreads();                    // order P write -> P read (cheap, safe)
        bf16x8 pf0 = *(const bf16x8*)&pw[ln16 * 72 + q * 8];
        bf16x8 pf1 = *(const bf16x8*)&pw[ln16 * 72 + 32 + q * 8];
        #pragma unroll
        for (int td = 0; td < 4; td++) {
            bf16x8 vf0 = *(const bf16x8*)&Vs[(td * 16 + ln16) * 64 + q * 8];
            bf16x8 vf1 = *(const bf16x8*)&Vs[(td * 16 + ln16) * 64 + 32 + q * 8];
            o[td] = __builtin_amdgcn_mfma_f32_16x16x32_bf16(pf0, vf0, o[td], 0, 0, 0);
            o[td] = __builtin_amdgcn_mfma_f32_16x16x32_bf16(pf1, vf1, o[td], 0, 0, 0);
        }
    }
    // epilogue: O / l, write bf16
    #pragma unroll
    for (int td = 0; td < 4; td++) {
        #pragma unroll
        for (int r = 0; r < 4; r++) {
            int row = q0 + wave * 16 + q * 4 + r;
            int col = h * 64 + td * 16 + ln16;
            ob[((size_t)(b * 1024 + row)) * 1024 + col] = f2bf(o[td][r] / lrow[r]);
        }
    }
}

// ------- weight transpose + bf16 convert: in fp32 [K][N] -> out bf16 [N][K] -------
__global__ __launch_bounds__(256) void wtrans_kernel(const float* __restrict__ in,
                                                     unsigned short* __restrict__ out,
                                                     int K, int N) {
    __shared__ float t[64][65];
    int n0 = blockIdx.x * 64, k0 = blockIdx.y * 64;
    for (int i = threadIdx.x; i < 4096; i += 256) {
        int kr = i >> 6, nc = i & 63;
        t[kr][nc] = in[(size_t)(k0 + kr) * N + n0 + nc];
    }
    __syncthreads();
    for (int i = threadIdx.x; i < 4096; i += 256) {
        int nr = i >> 6, kc = i & 63;
        out[(size_t)(n0 + nr) * K + k0 + kc] = f2bf(t[kc][nr]);
    }
}

// ------- bf16 MFMA GEMM: C = act(A@B + bias)[+C]; A[M][K] bf16, Bt[N][K] bf16 -----
// BMxBN tile, BK=32, 4 waves in WMxWN, each wave (BM/WM)x(BN/WN) of 16x16x32 MFMAs.
template <int BM, int BN, int WM, int WN, int ACT, bool ADDC, bool OUTBF16>
__global__ __launch_bounds__(256) void gemm_bf16(const unsigned short* __restrict__ A,
                                                 const unsigned short* __restrict__ Bt,
                                                 const float* __restrict__ bias,
                                                 float* __restrict__ Cf,
                                                 unsigned short* __restrict__ Cb,
                                                 int M, int N, int K) {
    constexpr int MT = BM / (WM * 16);
    constexpr int NT = BN / (WN * 16);
    __shared__ short As[BM * 32];
    __shared__ short Bs[BN * 32];
    int tid = threadIdx.x;
    int lane = tid & 63, wave = tid >> 6;
    int wm = wave / WN, wn = wave % WN;
    int ln16 = lane & 15, q = lane >> 4;
    int m0 = blockIdx.y * BM, n0 = blockIdx.x * BN;

    floatx4 acc[MT][NT];
    #pragma unroll
    for (int i = 0; i < MT; i++)
        #pragma unroll
        for (int j = 0; j < NT; j++) acc[i][j] = (floatx4){0.f, 0.f, 0.f, 0.f};

    int kSteps = K >> 5;
    for (int ks = 0; ks < kSteps; ks++) {
        int k0 = ks << 5;
        #pragma unroll
        for (int it = 0; it < BM / 64; it++) {
            int i = tid + it * 256;
            load_lds16(A + (size_t)(m0 + (i >> 2)) * K + k0 + (i & 3) * 8, &As[i * 8]);
        }
        #pragma unroll
        for (int it = 0; it < BN / 64; it++) {
            int i = tid + it * 256;
            load_lds16(Bt + (size_t)(n0 + (i >> 2)) * K + k0 + (i & 3) * 8, &Bs[i * 8]);
        }
        __syncthreads();
        bf16x8 af[MT], bf[NT];
        #pragma unroll
        for (int mi = 0; mi < MT; mi++)
            af[mi] = *(const bf16x8*)&As[(wm * (BM / WM) + mi * 16 + ln16) * 32 + q * 8];
        #pragma unroll
        for (int ni = 0; ni < NT; ni++)
            bf[ni] = *(const bf16x8*)&Bs[(wn * (BN / WN) + ni * 16 + ln16) * 32 + q * 8];
        #pragma unroll
        for (int mi = 0; mi < MT; mi++)
            #pragma unroll
            for (int ni = 0; ni < NT; ni++)
                acc[mi][ni] = __builtin_amdgcn_mfma_f32_16x16x32_bf16(af[mi], bf[ni], acc[mi][ni], 0, 0, 0);
        __syncthreads();
    }

    int q4 = q * 4;
    #pragma unroll
    for (int ni = 0; ni < NT; ni++) {
        int col = n0 + wn * (BN / WN) + ni * 16 + ln16;
        float bv = bias[col];
        #pragma unroll
        for (int mi = 0; mi < MT; mi++) {
            #pragma unroll
            for (int r = 0; r < 4; r++) {
                int row = m0 + wm * (BM / WM) + mi * 16 + q4 + r;
                size_t off = (size_t)row * N + col;
                float v = acc[mi][ni][r] + bv;
                if (ACT == 1) v = 0.5f * v * (1.f + erff(v * 0.70710678118654752f));
                if (ADDC) v += Cf[off];
                if (OUTBF16) Cb[off] = f2bf(v);
                else Cf[off] = v;
            }
        }
    }
}

// ---------------- unpatchify ----------------
__global__ void unpatchify_kernel(const float* __restrict__ xf, float* __restrict__ img) {
    int idx = blockIdx.x * 256 + threadIdx.x;
    int x = idx & 63, y = (idx >> 6) & 63, ch = (idx >> 12) & 63, b = idx >> 18;
    int hh = y >> 1, ww = x >> 1, p = y & 1, qq = x & 1;
    img[idx] = xf[((size_t)b * 1024 + hh * 32 + ww) * 256 + ch * 4 + p * 2 + qq];
}

// ---------------- conv1: 64->16 ch, 3x3, pad 1, relu ----------------
__global__ void conv1_kernel(const float* __restrict__ img, const float* __restrict__ w,
                             const float* __restrict__ bias, float* __restrict__ out) {
    int idx = blockIdx.x * 256 + threadIdx.x;
    int x = idx & 63, y = (idx >> 6) & 63, oc = (idx >> 12) & 15, b = idx >> 16;
    const float* ib = img + (size_t)b * 64 * 64 * 64;
    float s = bias[oc];
    for (int ic = 0; ic < 64; ic++) {
        const float* ip = ib + ic * 4096;
        const float* wp = w + (oc * 64 + ic) * 9;
        #pragma unroll
        for (int ky = 0; ky < 3; ky++) {
            int yy = y + ky - 1;
            if (yy < 0 || yy > 63) continue;
            #pragma unroll
            for (int kx = 0; kx < 3; kx++) {
                int xx = x + kx - 1;
                if (xx < 0 || xx > 63) continue;
                s += ip[yy * 64 + xx] * wp[ky * 3 + kx];
            }
        }
    }
    out[idx] = fmaxf(s, 0.f);
}

// ---------------- conv2: 16->3 ch, 3x3, pad 1 ----------------
__global__ void conv2_kernel(const float* __restrict__ in, const float* __restrict__ w,
                             const float* __restrict__ bias, float* __restrict__ out) {
    int idx = blockIdx.x * 256 + threadIdx.x;
    if (idx >= 24576) return;
    int x = idx & 63, y = (idx >> 6) & 63;
    int t = idx >> 12;
    int oc = t % 3, b = t / 3;
    const float* ib = in + (size_t)b * 16 * 4096;
    float s = bias[oc];
    for (int ic = 0; ic < 16; ic++) {
        const float* ip = ib + ic * 4096;
        const float* wp = w + (oc * 16 + ic) * 9;
        #pragma unroll
        for (int ky = 0; ky < 3; ky++) {
            int yy = y + ky - 1;
            if (yy < 0 || yy > 63) continue;
            #pragma unroll
            for (int kx = 0; kx < 3; kx++) {
                int xx = x + kx - 1;
                if (xx < 0 || xx > 63) continue;
                s += ip[yy * 64 + xx] * wp[ky * 3 + kx];
            }
        }
    }
    out[idx] = s;
}

// ---------------- launch ----------------
extern "C" void kernel_launch(void* const* d_in, const int* in_sizes, int n_in,
                              void* d_out, int out_size, void* d_ws, size_t ws_size,
                              hipStream_t stream) {
    const float* x_in   = (const float*)d_in[0];
    const float* qkv_w  = (const float*)d_in[1];
    const float* qkv_b  = (const float*)d_in[2];
    const float* proj_w = (const float*)d_in[3];
    const float* proj_b = (const float*)d_in[4];
    const float* nq_g   = (const float*)d_in[5];
    const float* nq_b   = (const float*)d_in[6];
    const float* nk_g   = (const float*)d_in[7];
    const float* nk_b   = (const float*)d_in[8];
    const float* n1_g   = (const float*)d_in[9];
    const float* n1_b   = (const float*)d_in[10];
    const float* n2_g   = (const float*)d_in[11];
    const float* n2_b   = (const float*)d_in[12];
    const float* fc1_w  = (const float*)d_in[13];
    const float* fc1_b  = (const float*)d_in[14];
    const float* fc2_w  = (const float*)d_in[15];
    const float* fc2_b  = (const float*)d_in[16];
    const float* fin_w  = (const float*)d_in[17];
    const float* fin_b  = (const float*)d_in[18];
    const float* c1_w   = (const float*)d_in[19];
    const float* c1_b   = (const float*)d_in[20];
    const float* c2_w   = (const float*)d_in[21];
    const float* c2_b   = (const float*)d_in[22];
    float* out = (float*)d_out;

    char* w = (char*)d_ws;
    float* xb           = (float*)w;          w += (size_t)2 * 1024 * 1024 * 4;
    unsigned short* hnb = (unsigned short*)w; w += (size_t)2 * 1024 * 1024 * 2;
    float* qkv          = (float*)w;          w += (size_t)2 * 1024 * 3072 * 4;
    unsigned short* obb = (unsigned short*)w; w += (size_t)2 * 1024 * 1024 * 2;
    unsigned short* mhb = (unsigned short*)w; w += (size_t)2 * 1024 * 4096 * 2;
    float* xf           = (float*)w;          w += (size_t)2 * 1024 * 256 * 4;
    float* img          = (float*)w;          w += (size_t)2 * 64 * 64 * 64 * 4;
    float* c1o          = (float*)w;          w += (size_t)2 * 16 * 64 * 64 * 4;
    unsigned short* Qb  = (unsigned short*)w; w += (size_t)2 * 1024 * 1024 * 2;
    unsigned short* Kb  = (unsigned short*)w; w += (size_t)2 * 1024 * 1024 * 2;
    unsigned short* Vt  = (unsigned short*)w; w += (size_t)2 * 16 * 64 * 1024 * 2;
    unsigned short* wq  = (unsigned short*)w; w += (size_t)1024 * 3072 * 2;
    unsigned short* wp  = (unsigned short*)w; w += (size_t)1024 * 1024 * 2;
    unsigned short* w1  = (unsigned short*)w; w += (size_t)1024 * 4096 * 2;
    unsigned short* w2  = (unsigned short*)w; w += (size_t)4096 * 1024 * 2;
    unsigned short* wfin= (unsigned short*)w; w += (size_t)1024 * 256 * 2;

    posembed_kernel<<<8192, 256, 0, stream>>>(x_in, xb);

    for (int i = 0; i < 4; i++) {
        wtrans_kernel<<<dim3(48, 16), 256, 0, stream>>>(qkv_w + (size_t)i * 1024 * 3072, wq, 1024, 3072);
        wtrans_kernel<<<dim3(16, 16), 256, 0, stream>>>(proj_w + (size_t)i * 1024 * 1024, wp, 1024, 1024);
        wtrans_kernel<<<dim3(64, 16), 256, 0, stream>>>(fc1_w + (size_t)i * 1024 * 4096, w1, 1024, 4096);
        wtrans_kernel<<<dim3(16, 64), 256, 0, stream>>>(fc2_w + (size_t)i * 4096 * 1024, w2, 4096, 1024);

        ln_kernel<<<2048, 256, 0, stream>>>(xb, hnb, n1_g + i * 1024, n1_b + i * 1024, 1e-5f, 1);
        gemm_bf16<128, 128, 2, 2, 0, false, false><<<dim3(24, 16), 256, 0, stream>>>(
            hnb, wq, qkv_b + i * 3072, qkv, nullptr, 2048, 3072, 1024);
        qknorm_kernel<<<8192, 256, 0, stream>>>(qkv, nq_g + i * 64, nq_b + i * 64,
                                                nk_g + i * 64, nk_b + i * 64, Qb, Kb);
        vtrans_kernel<<<dim3(16, 16, 2), 256, 0, stream>>>(qkv, Vt);
        attn_mfma<<<dim3(16, 16, 2), 256, 0, stream>>>(Qb, Kb, Vt, obb);
        gemm_bf16<64, 128, 2, 2, 0, true, false><<<dim3(8, 32), 256, 0, stream>>>(
            obb, wp, proj_b + i * 1024, xb, nullptr, 2048, 1024, 1024);
        ln_kernel<<<2048, 256, 0, stream>>>(xb, hnb, n2_g + i * 1024, n2_b + i * 1024, 1e-5f, 1);
        gemm_bf16<128, 128, 2, 2, 1, false, true><<<dim3(32, 16), 256, 0, stream>>>(
            hnb, w1, fc1_b + i * 4096, nullptr, mhb, 2048, 4096, 1024);
        gemm_bf16<64, 128, 2, 2, 0, true, false><<<dim3(8, 32), 256, 0, stream>>>(
            mhb, w2, fc2_b + i * 1024, xb, nullptr, 2048, 1024, 4096);
    }

    wtrans_kernel<<<dim3(4, 16), 256, 0, stream>>>(fin_w, wfin, 1024, 256);
    ln_kernel<<<2048, 256, 0, stream>>>(xb, hnb, nullptr, nullptr, 1e-6f, 0);
    gemm_bf16<64, 64, 2, 2, 0, false, false><<<dim3(4, 32), 256, 0, stream>>>(
        hnb, wfin, fin_b, xf, nullptr, 2048, 256, 1024);
    unpatchify_kernel<<<2048, 256, 0, stream>>>(xf, img);
    conv1_kernel<<<512, 256, 0, stream>>>(img, c1_w, c1_b, c1o);
    conv2_kernel<<<96, 256, 0, stream>>>(c1o, c2_w, c2_b, out);
}

// Round 5
// 1274.205 us; speedup vs baseline: 6.8135x; 1.0448x over previous
//
#include <hip/hip_runtime.h>
#include <hip/hip_bf16.h>
#include <math.h>

typedef float floatx4 __attribute__((ext_vector_type(4)));
typedef short bf16x8 __attribute__((ext_vector_type(8)));   // 8 bf16 in 4 VGPRs

__device__ __forceinline__ unsigned short f2bf(float x) {
    union { float f; unsigned int u; } v; v.f = x;
    unsigned int r = v.u + 0x7fffu + ((v.u >> 16) & 1u);    // RNE
    return (unsigned short)(r >> 16);
}

__device__ __forceinline__ void load_lds16(const void* g, void* l) {
    __builtin_amdgcn_global_load_lds(
        (const __attribute__((address_space(1))) unsigned int*)(uintptr_t)g,
        (__attribute__((address_space(3))) unsigned int*)(uintptr_t)l, 16, 0, 0);
}

// ---------------- pos embed + input add ----------------
__global__ void posembed_kernel(const float* __restrict__ xin, float* __restrict__ xb) {
    int idx = blockIdx.x * 256 + threadIdx.x;     // 2*1024*1024
    int c = idx & 1023;
    int n = (idx >> 10) & 1023;
    int pos = (c < 512) ? (n & 31) : (n >> 5);
    int cc = c & 511;
    int k = cc & 255;
    double om = exp(-(double)k * (9.210340371976184 / 256.0));
    double arg = (double)pos * om;
    float e = (float)((cc < 256) ? sin(arg) : cos(arg));
    xb[idx] = xin[idx] + e;
}

// ---------------- layernorm over C=1024, bf16 output ----------------
__global__ __launch_bounds__(256) void ln_kernel(const float* __restrict__ X,
                                                 unsigned short* __restrict__ Y,
                                                 const float* __restrict__ g,
                                                 const float* __restrict__ b,
                                                 float eps, int affine) {
    int row = blockIdx.x;
    const float4* xr = (const float4*)(X + (size_t)row * 1024);
    float4 x = xr[threadIdx.x];
    float s = x.x + x.y + x.z + x.w;
    float sq = x.x * x.x + x.y * x.y + x.z * x.z + x.w * x.w;
    __shared__ float red[8];
    #pragma unroll
    for (int off = 32; off; off >>= 1) { s += __shfl_xor(s, off); sq += __shfl_xor(sq, off); }
    int wid = threadIdx.x >> 6, lane = threadIdx.x & 63;
    if (!lane) { red[wid] = s; red[wid + 4] = sq; }
    __syncthreads();
    s = red[0] + red[1] + red[2] + red[3];
    sq = red[4] + red[5] + red[6] + red[7];
    float mu = s * (1.f / 1024.f);
    float var = sq * (1.f / 1024.f) - mu * mu;
    float rs = rsqrtf(var + eps);
    int c = threadIdx.x * 4;
    float4 y;
    if (affine) {
        y.x = (x.x - mu) * rs * g[c + 0] + b[c + 0];
        y.y = (x.y - mu) * rs * g[c + 1] + b[c + 1];
        y.z = (x.z - mu) * rs * g[c + 2] + b[c + 2];
        y.w = (x.w - mu) * rs * g[c + 3] + b[c + 3];
    } else {
        y.x = (x.x - mu) * rs; y.y = (x.y - mu) * rs;
        y.z = (x.z - mu) * rs; y.w = (x.w - mu) * rs;
    }
    ushort4 o;
    o.x = f2bf(y.x); o.y = f2bf(y.y); o.z = f2bf(y.z); o.w = f2bf(y.w);
    *(ushort4*)(Y + (size_t)row * 1024 + c) = o;
}

// ---- merged qk-norm + V transpose: one pass over qkv ----
// grid (16 l-tiles, 16 heads, 2 b); writes Qb (x0.125), Kb, Vt[b][h][d][l] all bf16
__global__ __launch_bounds__(256) void qkvprep_kernel(const float* __restrict__ qkv,
                                                      const float* __restrict__ nqg,
                                                      const float* __restrict__ nqb,
                                                      const float* __restrict__ nkg,
                                                      const float* __restrict__ nkb,
                                                      unsigned short* __restrict__ Qb,
                                                      unsigned short* __restrict__ Kb,
                                                      unsigned short* __restrict__ Vt) {
    __shared__ float t[64][65];
    int tid = threadIdx.x;
    int l0 = blockIdx.x * 64, h = blockIdx.y, b = blockIdx.z;
    // V transpose through LDS
    for (int i = tid; i < 4096; i += 256) {
        int lr = i >> 6, dd = i & 63;
        t[lr][dd] = qkv[((size_t)(b * 1024 + l0 + lr)) * 3072 + 2048 + h * 64 + dd];
    }
    __syncthreads();
    for (int i = tid; i < 4096; i += 256) {
        int dd = i >> 6, lc = i & 63;
        Vt[((size_t)((b * 16 + h) * 64 + dd)) * 1024 + l0 + lc] = f2bf(t[lc][dd]);
    }
    // qk-norm: wave w handles rows l_local = w + 4*i
    int wave = tid >> 6, lane = tid & 63;
    float gq = nqg[lane], bq = nqb[lane], gk = nkg[lane], bk = nkb[lane];
    for (int i = 0; i < 16; i++) {
        int l = l0 + wave + 4 * i;
        const float* base = qkv + (size_t)(b * 1024 + l) * 3072 + h * 64 + lane;
        #pragma unroll
        for (int part = 0; part < 2; part++) {
            float v = base[part * 1024];
            float s = v, sq = v * v;
            #pragma unroll
            for (int off = 32; off; off >>= 1) { s += __shfl_xor(s, off); sq += __shfl_xor(sq, off); }
            float mu = s * (1.f / 64.f);
            float var = sq * (1.f / 64.f) - mu * mu;
            float rs = rsqrtf(var + 1e-5f);
            float y = (v - mu) * rs * (part ? gk : gq) + (part ? bk : bq);
            unsigned short* dst = part ? Kb : Qb;
            dst[(size_t)(b * 1024 + l) * 1024 + h * 64 + lane] = f2bf(y * (part ? 1.f : 0.125f));
        }
    }
}

// ---- MFMA flash attention: block = (64 q-rows, head, b); 4 waves x 16 rows ----
__global__ __launch_bounds__(256) void attn_mfma(const unsigned short* __restrict__ Qb,
                                                 const unsigned short* __restrict__ Kb,
                                                 const unsigned short* __restrict__ Vt,
                                                 unsigned short* __restrict__ ob) {
    __shared__ short Ks[64 * 64];       // [l_local][d]
    __shared__ short Vs[64 * 64];       // [d][l_local]
    __shared__ short Pl[4][16 * 72];    // per-wave P tile, padded stride 72
    int tid = threadIdx.x;
    int lane = tid & 63, wave = tid >> 6;
    int ln16 = lane & 15, q = lane >> 4;
    int b = blockIdx.z, h = blockIdx.y, q0 = blockIdx.x * 64;

    const unsigned short* qrow = Qb + ((size_t)(b * 1024 + q0 + wave * 16 + ln16)) * 1024 + h * 64;
    bf16x8 qf0 = *(const bf16x8*)(qrow + q * 8);
    bf16x8 qf1 = *(const bf16x8*)(qrow + 32 + q * 8);

    floatx4 o[4];
    #pragma unroll
    for (int td = 0; td < 4; td++) o[td] = (floatx4){0.f, 0.f, 0.f, 0.f};
    float mrow[4] = {-1e30f, -1e30f, -1e30f, -1e30f};
    float lrow[4] = {0.f, 0.f, 0.f, 0.f};

    const unsigned short* kbase0 = Kb + ((size_t)(b * 1024)) * 1024 + h * 64;
    const unsigned short* vbase0 = Vt + ((size_t)((b * 16 + h) * 64)) * 1024;

    for (int ch = 0; ch < 16; ch++) {
        int l0 = ch * 64;
        __syncthreads();
        #pragma unroll
        for (int it = 0; it < 2; it++) {
            int j = tid + it * 256;
            int row = j >> 3, g = j & 7;
            load_lds16(kbase0 + (size_t)(l0 + row) * 1024 + g * 8, &Ks[j * 8]);
            load_lds16(vbase0 + (size_t)row * 1024 + l0 + g * 8, &Vs[j * 8]);
        }
        __syncthreads();

        floatx4 s[4];
        #pragma unroll
        for (int t = 0; t < 4; t++) {
            s[t] = (floatx4){0.f, 0.f, 0.f, 0.f};
            bf16x8 kf0 = *(const bf16x8*)&Ks[(t * 16 + ln16) * 64 + q * 8];
            bf16x8 kf1 = *(const bf16x8*)&Ks[(t * 16 + ln16) * 64 + 32 + q * 8];
            s[t] = __builtin_amdgcn_mfma_f32_16x16x32_bf16(qf0, kf0, s[t], 0, 0, 0);
            s[t] = __builtin_amdgcn_mfma_f32_16x16x32_bf16(qf1, kf1, s[t], 0, 0, 0);
        }
        float cm[4], rs[4], p[4][4];
        #pragma unroll
        for (int r = 0; r < 4; r++)
            cm[r] = fmaxf(fmaxf(s[0][r], s[1][r]), fmaxf(s[2][r], s[3][r]));
        #pragma unroll
        for (int off = 1; off < 16; off <<= 1) {
            #pragma unroll
            for (int r = 0; r < 4; r++) cm[r] = fmaxf(cm[r], __shfl_xor(cm[r], off));
        }
        #pragma unroll
        for (int r = 0; r < 4; r++) {
            float mnew = fmaxf(mrow[r], cm[r]);
            float alpha = __expf(mrow[r] - mnew);
            mrow[r] = mnew;
            rs[r] = 0.f;
            #pragma unroll
            for (int t = 0; t < 4; t++) {
                p[t][r] = __expf(s[t][r] - mnew);
                rs[r] += p[t][r];
            }
            lrow[r] *= alpha;
            #pragma unroll
            for (int td = 0; td < 4; td++) o[td][r] *= alpha;
        }
        #pragma unroll
        for (int off = 1; off < 16; off <<= 1) {
            #pragma unroll
            for (int r = 0; r < 4; r++) rs[r] += __shfl_xor(rs[r], off);
        }
        #pragma unroll
        for (int r = 0; r < 4; r++) lrow[r] += rs[r];

        short* pw = &Pl[wave][0];
        #pragma unroll
        for (int t = 0; t < 4; t++)
            #pragma unroll
            for (int r = 0; r < 4; r++)
                pw[(q * 4 + r) * 72 + t * 16 + ln16] = (short)f2bf(p[t][r]);
        __syncthreads();
        bf16x8 pf0 = *(const bf16x8*)&pw[ln16 * 72 + q * 8];
        bf16x8 pf1 = *(const bf16x8*)&pw[ln16 * 72 + 32 + q * 8];
        #pragma unroll
        for (int td = 0; td < 4; td++) {
            bf16x8 vf0 = *(const bf16x8*)&Vs[(td * 16 + ln16) * 64 + q * 8];
            bf16x8 vf1 = *(const bf16x8*)&Vs[(td * 16 + ln16) * 64 + 32 + q * 8];
            o[td] = __builtin_amdgcn_mfma_f32_16x16x32_bf16(pf0, vf0, o[td], 0, 0, 0);
            o[td] = __builtin_amdgcn_mfma_f32_16x16x32_bf16(pf1, vf1, o[td], 0, 0, 0);
        }
    }
    #pragma unroll
    for (int td = 0; td < 4; td++) {
        #pragma unroll
        for (int r = 0; r < 4; r++) {
            int row = q0 + wave * 16 + q * 4 + r;
            int col = h * 64 + td * 16 + ln16;
            ob[((size_t)(b * 1024 + row)) * 1024 + col] = f2bf(o[td][r] / lrow[r]);
        }
    }
}

// ------- batched weight transpose + bf16: in fp32 [z][K][N] -> out bf16 [z][N][K] ----
__global__ __launch_bounds__(256) void wtrans_kernel(const float* __restrict__ in,
                                                     unsigned short* __restrict__ out,
                                                     int K, int N) {
    __shared__ float t[64][65];
    int n0 = blockIdx.x * 64, k0 = blockIdx.y * 64, z = blockIdx.z;
    in  += (size_t)z * K * N;
    out += (size_t)z * N * K;
    for (int i = threadIdx.x; i < 4096; i += 256) {
        int kr = i >> 6, nc = i & 63;
        t[kr][nc] = in[(size_t)(k0 + kr) * N + n0 + nc];
    }
    __syncthreads();
    for (int i = threadIdx.x; i < 4096; i += 256) {
        int nr = i >> 6, kc = i & 63;
        out[(size_t)(n0 + nr) * K + k0 + kc] = f2bf(t[kc][nr]);
    }
}

// ------- bf16 MFMA GEMM: C = act(A@B + bias)[+C]; A[M][K] bf16, Bt[N][K] bf16 -----
template <int BM, int BN, int WM, int WN, int ACT, bool ADDC, bool OUTBF16>
__global__ __launch_bounds__(256) void gemm_bf16(const unsigned short* __restrict__ A,
                                                 const unsigned short* __restrict__ Bt,
                                                 const float* __restrict__ bias,
                                                 float* __restrict__ Cf,
                                                 unsigned short* __restrict__ Cb,
                                                 int M, int N, int K) {
    constexpr int MT = BM / (WM * 16);
    constexpr int NT = BN / (WN * 16);
    __shared__ short As[BM * 32];
    __shared__ short Bs[BN * 32];
    int tid = threadIdx.x;
    int lane = tid & 63, wave = tid >> 6;
    int wm = wave / WN, wn = wave % WN;
    int ln16 = lane & 15, q = lane >> 4;
    int m0 = blockIdx.y * BM, n0 = blockIdx.x * BN;

    floatx4 acc[MT][NT];
    #pragma unroll
    for (int i = 0; i < MT; i++)
        #pragma unroll
        for (int j = 0; j < NT; j++) acc[i][j] = (floatx4){0.f, 0.f, 0.f, 0.f};

    int kSteps = K >> 5;
    for (int ks = 0; ks < kSteps; ks++) {
        int k0 = ks << 5;
        #pragma unroll
        for (int it = 0; it < BM / 64; it++) {
            int i = tid + it * 256;
            load_lds16(A + (size_t)(m0 + (i >> 2)) * K + k0 + (i & 3) * 8, &As[i * 8]);
        }
        #pragma unroll
        for (int it = 0; it < BN / 64; it++) {
            int i = tid + it * 256;
            load_lds16(Bt + (size_t)(n0 + (i >> 2)) * K + k0 + (i & 3) * 8, &Bs[i * 8]);
        }
        __syncthreads();
        bf16x8 af[MT], bf[NT];
        #pragma unroll
        for (int mi = 0; mi < MT; mi++)
            af[mi] = *(const bf16x8*)&As[(wm * (BM / WM) + mi * 16 + ln16) * 32 + q * 8];
        #pragma unroll
        for (int ni = 0; ni < NT; ni++)
            bf[ni] = *(const bf16x8*)&Bs[(wn * (BN / WN) + ni * 16 + ln16) * 32 + q * 8];
        #pragma unroll
        for (int mi = 0; mi < MT; mi++)
            #pragma unroll
            for (int ni = 0; ni < NT; ni++)
                acc[mi][ni] = __builtin_amdgcn_mfma_f32_16x16x32_bf16(af[mi], bf[ni], acc[mi][ni], 0, 0, 0);
        __syncthreads();
    }

    int q4 = q * 4;
    #pragma unroll
    for (int ni = 0; ni < NT; ni++) {
        int col = n0 + wn * (BN / WN) + ni * 16 + ln16;
        float bv = bias[col];
        #pragma unroll
        for (int mi = 0; mi < MT; mi++) {
            #pragma unroll
            for (int r = 0; r < 4; r++) {
                int row = m0 + wm * (BM / WM) + mi * 16 + q4 + r;
                size_t off = (size_t)row * N + col;
                float v = acc[mi][ni][r] + bv;
                if (ACT == 1) v = 0.5f * v * (1.f + erff(v * 0.70710678118654752f));
                if (ADDC) v += Cf[off];
                if (OUTBF16) Cb[off] = f2bf(v);
                else Cf[off] = v;
            }
        }
    }
}

// ---------------- unpatchify ----------------
__global__ void unpatchify_kernel(const float* __restrict__ xf, float* __restrict__ img) {
    int idx = blockIdx.x * 256 + threadIdx.x;
    int x = idx & 63, y = (idx >> 6) & 63, ch = (idx >> 12) & 63, b = idx >> 18;
    int hh = y >> 1, ww = x >> 1, p = y & 1, qq = x & 1;
    img[idx] = xf[((size_t)b * 1024 + hh * 32 + ww) * 256 + ch * 4 + p * 2 + qq];
}

// ------- conv1: 64->16, 3x3, pad1, relu. block = (y, b); LDS-staged rows+weights ----
__global__ __launch_bounds__(256) void conv1_kernel(const float* __restrict__ img,
                                                    const float* __restrict__ w,
                                                    const float* __restrict__ bias,
                                                    float* __restrict__ out) {
    __shared__ float Ls[64 * 3 * 66];   // [ic][ky][x+1] halo-padded, 50.7 KB
    __shared__ float Ws[16 * 580];      // [oc][ic*9+k], stride 580 breaks bank alias
    int tid = threadIdx.x;
    int y = blockIdx.x, b = blockIdx.y;
    for (int i = tid; i < 9216; i += 256) {
        int oc = i / 576, rem = i % 576;
        Ws[oc * 580 + rem] = w[i];
    }
    for (int i = tid; i < 12288; i += 256) {
        int r = i >> 6, x = i & 63;
        int ic = r / 3, ky = r % 3;
        int yy = y + ky - 1;
        float v = (yy >= 0 && yy < 64) ? img[((size_t)(b * 64 + ic) * 64 + yy) * 64 + x] : 0.f;
        Ls[(ic * 3 + ky) * 66 + x + 1] = v;
        if (x == 0)  Ls[(ic * 3 + ky) * 66 + 0]  = 0.f;
        if (x == 63) Ls[(ic * 3 + ky) * 66 + 65] = 0.f;
    }
    __syncthreads();
    int oc = tid >> 4, xg = (tid & 15) * 4;
    float bv = bias[oc];
    float acc0 = bv, acc1 = bv, acc2 = bv, acc3 = bv;
    for (int ic = 0; ic < 64; ic++) {
        const float* wr = &Ws[oc * 580 + ic * 9];
        float w00 = wr[0], w01 = wr[1], w02 = wr[2];
        float w10 = wr[3], w11 = wr[4], w12 = wr[5];
        float w20 = wr[6], w21 = wr[7], w22 = wr[8];
        const float* l0 = &Ls[(ic * 3 + 0) * 66 + xg];
        const float* l1 = &Ls[(ic * 3 + 1) * 66 + xg];
        const float* l2 = &Ls[(ic * 3 + 2) * 66 + xg];
        float a0 = l0[0], a1 = l0[1], a2 = l0[2], a3 = l0[3], a4 = l0[4], a5 = l0[5];
        float b0 = l1[0], b1 = l1[1], b2 = l1[2], b3 = l1[3], b4 = l1[4], b5 = l1[5];
        float c0 = l2[0], c1 = l2[1], c2 = l2[2], c3 = l2[3], c4 = l2[4], c5 = l2[5];
        acc0 += a0*w00 + a1*w01 + a2*w02 + b0*w10 + b1*w11 + b2*w12 + c0*w20 + c1*w21 + c2*w22;
        acc1 += a1*w00 + a2*w01 + a3*w02 + b1*w10 + b2*w11 + b3*w12 + c1*w20 + c2*w21 + c3*w22;
        acc2 += a2*w00 + a3*w01 + a4*w02 + b2*w10 + b3*w11 + b4*w12 + c2*w20 + c3*w21 + c4*w22;
        acc3 += a3*w00 + a4*w01 + a5*w02 + b3*w10 + b4*w11 + b5*w12 + c3*w20 + c4*w21 + c5*w22;
    }
    float* op = out + (((size_t)(b * 16 + oc) * 64 + y) * 64 + xg);
    op[0] = fmaxf(acc0, 0.f);
    op[1] = fmaxf(acc1, 0.f);
    op[2] = fmaxf(acc2, 0.f);
    op[3] = fmaxf(acc3, 0.f);
}

// ------- conv2: 16->3, 3x3, pad1. block = (y, b) ----
__global__ __launch_bounds__(256) void conv2_kernel(const float* __restrict__ in,
                                                    const float* __restrict__ w,
                                                    const float* __restrict__ bias,
                                                    float* __restrict__ out) {
    __shared__ float Ls[16 * 3 * 66];
    __shared__ float Ws[3 * 160];
    int tid = threadIdx.x;
    int y = blockIdx.x, b = blockIdx.y;
    for (int i = tid; i < 432; i += 256) {
        int oc = i / 144, rem = i % 144;
        Ws[oc * 160 + rem] = w[i];
    }
    for (int i = tid; i < 3072; i += 256) {
        int r = i >> 6, x = i & 63;
        int ic = r / 3, ky = r % 3;
        int yy = y + ky - 1;
        float v = (yy >= 0 && yy < 64) ? in[((size_t)(b * 16 + ic) * 64 + yy) * 64 + x] : 0.f;
        Ls[(ic * 3 + ky) * 66 + x + 1] = v;
        if (x == 0)  Ls[(ic * 3 + ky) * 66 + 0]  = 0.f;
        if (x == 63) Ls[(ic * 3 + ky) * 66 + 65] = 0.f;
    }
    __syncthreads();
    int oc = tid >> 6, x = tid & 63;
    if (oc < 3) {
        float acc = bias[oc];
        for (int ic = 0; ic < 16; ic++) {
            const float* wr = &Ws[oc * 160 + ic * 9];
            const float* l0 = &Ls[(ic * 3 + 0) * 66 + x];
            const float* l1 = &Ls[(ic * 3 + 1) * 66 + x];
            const float* l2 = &Ls[(ic * 3 + 2) * 66 + x];
            acc += l0[0]*wr[0] + l0[1]*wr[1] + l0[2]*wr[2]
                 + l1[0]*wr[3] + l1[1]*wr[4] + l1[2]*wr[5]
                 + l2[0]*wr[6] + l2[1]*wr[7] + l2[2]*wr[8];
        }
        out[((size_t)(b * 3 + oc) * 64 + y) * 64 + x] = acc;
    }
}

// ---------------- launch ----------------
extern "C" void kernel_launch(void* const* d_in, const int* in_sizes, int n_in,
                              void* d_out, int out_size, void* d_ws, size_t ws_size,
                              hipStream_t stream) {
    const float* x_in   = (const float*)d_in[0];
    const float* qkv_w  = (const float*)d_in[1];
    const float* qkv_b  = (const float*)d_in[2];
    const float* proj_w = (const float*)d_in[3];
    const float* proj_b = (const float*)d_in[4];
    const float* nq_g   = (const float*)d_in[5];
    const float* nq_b   = (const float*)d_in[6];
    const float* nk_g   = (const float*)d_in[7];
    const float* nk_b   = (const float*)d_in[8];
    const float* n1_g   = (const float*)d_in[9];
    const float* n1_b   = (const float*)d_in[10];
    const float* n2_g   = (const float*)d_in[11];
    const float* n2_b   = (const float*)d_in[12];
    const float* fc1_w  = (const float*)d_in[13];
    const float* fc1_b  = (const float*)d_in[14];
    const float* fc2_w  = (const float*)d_in[15];
    const float* fc2_b  = (const float*)d_in[16];
    const float* fin_w  = (const float*)d_in[17];
    const float* fin_b  = (const float*)d_in[18];
    const float* c1_w   = (const float*)d_in[19];
    const float* c1_b   = (const float*)d_in[20];
    const float* c2_w   = (const float*)d_in[21];
    const float* c2_b   = (const float*)d_in[22];
    float* out = (float*)d_out;

    char* w = (char*)d_ws;
    float* xb           = (float*)w;          w += (size_t)2 * 1024 * 1024 * 4;
    unsigned short* hnb = (unsigned short*)w; w += (size_t)2 * 1024 * 1024 * 2;
    float* qkv          = (float*)w;          w += (size_t)2 * 1024 * 3072 * 4;
    unsigned short* obb = (unsigned short*)w; w += (size_t)2 * 1024 * 1024 * 2;
    unsigned short* mhb = (unsigned short*)w; w += (size_t)2 * 1024 * 4096 * 2;
    float* xf           = (float*)w;          w += (size_t)2 * 1024 * 256 * 4;
    float* img          = (float*)w;          w += (size_t)2 * 64 * 64 * 64 * 4;
    float* c1o          = (float*)w;          w += (size_t)2 * 16 * 64 * 64 * 4;
    unsigned short* Qb  = (unsigned short*)w; w += (size_t)2 * 1024 * 1024 * 2;
    unsigned short* Kb  = (unsigned short*)w; w += (size_t)2 * 1024 * 1024 * 2;
    unsigned short* Vt  = (unsigned short*)w; w += (size_t)2 * 16 * 64 * 1024 * 2;
    unsigned short* WQ  = (unsigned short*)w; w += (size_t)4 * 1024 * 3072 * 2;   // all blocks
    unsigned short* WP  = (unsigned short*)w; w += (size_t)4 * 1024 * 1024 * 2;
    unsigned short* W1  = (unsigned short*)w; w += (size_t)4 * 1024 * 4096 * 2;
    unsigned short* W2  = (unsigned short*)w; w += (size_t)4 * 4096 * 1024 * 2;
    unsigned short* WF  = (unsigned short*)w; w += (size_t)1024 * 256 * 2;

    // all weight transposes up front (batched over the 4 blocks)
    wtrans_kernel<<<dim3(48, 16, 4), 256, 0, stream>>>(qkv_w, WQ, 1024, 3072);
    wtrans_kernel<<<dim3(16, 16, 4), 256, 0, stream>>>(proj_w, WP, 1024, 1024);
    wtrans_kernel<<<dim3(64, 16, 4), 256, 0, stream>>>(fc1_w, W1, 1024, 4096);
    wtrans_kernel<<<dim3(16, 64, 4), 256, 0, stream>>>(fc2_w, W2, 4096, 1024);
    wtrans_kernel<<<dim3(4, 16, 1), 256, 0, stream>>>(fin_w, WF, 1024, 256);

    posembed_kernel<<<8192, 256, 0, stream>>>(x_in, xb);

    for (int i = 0; i < 4; i++) {
        ln_kernel<<<2048, 256, 0, stream>>>(xb, hnb, n1_g + i * 1024, n1_b + i * 1024, 1e-5f, 1);
        gemm_bf16<128, 128, 2, 2, 0, false, false><<<dim3(24, 16), 256, 0, stream>>>(
            hnb, WQ + (size_t)i * 3072 * 1024, qkv_b + i * 3072, qkv, nullptr, 2048, 3072, 1024);
        qkvprep_kernel<<<dim3(16, 16, 2), 256, 0, stream>>>(
            qkv, nq_g + i * 64, nq_b + i * 64, nk_g + i * 64, nk_b + i * 64, Qb, Kb, Vt);
        attn_mfma<<<dim3(16, 16, 2), 256, 0, stream>>>(Qb, Kb, Vt, obb);
        gemm_bf16<64, 128, 2, 2, 0, true, false><<<dim3(8, 32), 256, 0, stream>>>(
            obb, WP + (size_t)i * 1024 * 1024, proj_b + i * 1024, xb, nullptr, 2048, 1024, 1024);
        ln_kernel<<<2048, 256, 0, stream>>>(xb, hnb, n2_g + i * 1024, n2_b + i * 1024, 1e-5f, 1);
        gemm_bf16<128, 128, 2, 2, 1, false, true><<<dim3(32, 16), 256, 0, stream>>>(
            hnb, W1 + (size_t)i * 4096 * 1024, fc1_b + i * 4096, nullptr, mhb, 2048, 4096, 1024);
        gemm_bf16<64, 128, 2, 2, 0, true, false><<<dim3(8, 32), 256, 0, stream>>>(
            mhb, W2 + (size_t)i * 1024 * 4096, fc2_b + i * 1024, xb, nullptr, 2048, 1024, 4096);
    }

    ln_kernel<<<2048, 256, 0, stream>>>(xb, hnb, nullptr, nullptr, 1e-6f, 0);
    gemm_bf16<64, 64, 2, 2, 0, false, false><<<dim3(4, 32), 256, 0, stream>>>(
        hnb, WF, fin_b, xf, nullptr, 2048, 256, 1024);
    unpatchify_kernel<<<2048, 256, 0, stream>>>(xf, img);
    conv1_kernel<<<dim3(64, 2), 256, 0, stream>>>(img, c1_w, c1_b, c1o);
    conv2_kernel<<<dim3(64, 2), 256, 0, stream>>>(c1o, c2_w, c2_b, out);
}

// Round 6
// 1017.565 us; speedup vs baseline: 8.5319x; 1.2522x over previous
//
#include <hip/hip_runtime.h>
#include <hip/hip_bf16.h>
#include <math.h>

typedef float floatx4 __attribute__((ext_vector_type(4)));
typedef short bf16x8 __attribute__((ext_vector_type(8)));   // 8 bf16 in 4 VGPRs

__device__ __forceinline__ unsigned short f2bf(float x) {
    union { float f; unsigned int u; } v; v.f = x;
    unsigned int r = v.u + 0x7fffu + ((v.u >> 16) & 1u);    // RNE
    return (unsigned short)(r >> 16);
}

__device__ __forceinline__ void load_lds16(const void* g, void* l) {
    __builtin_amdgcn_global_load_lds(
        (const __attribute__((address_space(1))) unsigned int*)(uintptr_t)g,
        (__attribute__((address_space(3))) unsigned int*)(uintptr_t)l, 16, 0, 0);
}

// ---------------- pos embed + input add ----------------
__global__ void posembed_kernel(const float* __restrict__ xin, float* __restrict__ xb) {
    int idx = blockIdx.x * 256 + threadIdx.x;     // 2*1024*1024
    int c = idx & 1023;
    int n = (idx >> 10) & 1023;
    int pos = (c < 512) ? (n & 31) : (n >> 5);
    int cc = c & 511;
    int k = cc & 255;
    double om = exp(-(double)k * (9.210340371976184 / 256.0));
    double arg = (double)pos * om;
    float e = (float)((cc < 256) ? sin(arg) : cos(arg));
    xb[idx] = xin[idx] + e;
}

// ---------------- layernorm over C=1024, bf16 output ----------------
__global__ __launch_bounds__(256) void ln_kernel(const float* __restrict__ X,
                                                 unsigned short* __restrict__ Y,
                                                 const float* __restrict__ g,
                                                 const float* __restrict__ b,
                                                 float eps, int affine) {
    int row = blockIdx.x;
    const float4* xr = (const float4*)(X + (size_t)row * 1024);
    float4 x = xr[threadIdx.x];
    float s = x.x + x.y + x.z + x.w;
    float sq = x.x * x.x + x.y * x.y + x.z * x.z + x.w * x.w;
    __shared__ float red[8];
    #pragma unroll
    for (int off = 32; off; off >>= 1) { s += __shfl_xor(s, off); sq += __shfl_xor(sq, off); }
    int wid = threadIdx.x >> 6, lane = threadIdx.x & 63;
    if (!lane) { red[wid] = s; red[wid + 4] = sq; }
    __syncthreads();
    s = red[0] + red[1] + red[2] + red[3];
    sq = red[4] + red[5] + red[6] + red[7];
    float mu = s * (1.f / 1024.f);
    float var = sq * (1.f / 1024.f) - mu * mu;
    float rs = rsqrtf(var + eps);
    int c = threadIdx.x * 4;
    float4 y;
    if (affine) {
        y.x = (x.x - mu) * rs * g[c + 0] + b[c + 0];
        y.y = (x.y - mu) * rs * g[c + 1] + b[c + 1];
        y.z = (x.z - mu) * rs * g[c + 2] + b[c + 2];
        y.w = (x.w - mu) * rs * g[c + 3] + b[c + 3];
    } else {
        y.x = (x.x - mu) * rs; y.y = (x.y - mu) * rs;
        y.z = (x.z - mu) * rs; y.w = (x.w - mu) * rs;
    }
    ushort4 o;
    o.x = f2bf(y.x); o.y = f2bf(y.y); o.z = f2bf(y.z); o.w = f2bf(y.w);
    *(ushort4*)(Y + (size_t)row * 1024 + c) = o;
}

// ---- merged qk-norm + V transpose: one pass over qkv ----
__global__ __launch_bounds__(256) void qkvprep_kernel(const float* __restrict__ qkv,
                                                      const float* __restrict__ nqg,
                                                      const float* __restrict__ nqb,
                                                      const float* __restrict__ nkg,
                                                      const float* __restrict__ nkb,
                                                      unsigned short* __restrict__ Qb,
                                                      unsigned short* __restrict__ Kb,
                                                      unsigned short* __restrict__ Vt) {
    __shared__ float t[64][65];
    int tid = threadIdx.x;
    int l0 = blockIdx.x * 64, h = blockIdx.y, b = blockIdx.z;
    for (int i = tid; i < 4096; i += 256) {
        int lr = i >> 6, dd = i & 63;
        t[lr][dd] = qkv[((size_t)(b * 1024 + l0 + lr)) * 3072 + 2048 + h * 64 + dd];
    }
    __syncthreads();
    for (int i = tid; i < 4096; i += 256) {
        int dd = i >> 6, lc = i & 63;
        Vt[((size_t)((b * 16 + h) * 64 + dd)) * 1024 + l0 + lc] = f2bf(t[lc][dd]);
    }
    int wave = tid >> 6, lane = tid & 63;
    float gq = nqg[lane], bq = nqb[lane], gk = nkg[lane], bk = nkb[lane];
    for (int i = 0; i < 16; i++) {
        int l = l0 + wave + 4 * i;
        const float* base = qkv + (size_t)(b * 1024 + l) * 3072 + h * 64 + lane;
        #pragma unroll
        for (int part = 0; part < 2; part++) {
            float v = base[part * 1024];
            float s = v, sq = v * v;
            #pragma unroll
            for (int off = 32; off; off >>= 1) { s += __shfl_xor(s, off); sq += __shfl_xor(sq, off); }
            float mu = s * (1.f / 64.f);
            float var = sq * (1.f / 64.f) - mu * mu;
            float rs = rsqrtf(var + 1e-5f);
            float y = (v - mu) * rs * (part ? gk : gq) + (part ? bk : bq);
            unsigned short* dst = part ? Kb : Qb;
            dst[(size_t)(b * 1024 + l) * 1024 + h * 64 + lane] = f2bf(y * (part ? 1.f : 0.125f));
        }
    }
}

// ---- MFMA flash attention: block = (64 q-rows, head, b); 4 waves x 16 rows ----
__global__ __launch_bounds__(256) void attn_mfma(const unsigned short* __restrict__ Qb,
                                                 const unsigned short* __restrict__ Kb,
                                                 const unsigned short* __restrict__ Vt,
                                                 unsigned short* __restrict__ ob) {
    __shared__ short Ks[64 * 64];
    __shared__ short Vs[64 * 64];
    __shared__ short Pl[4][16 * 72];
    int tid = threadIdx.x;
    int lane = tid & 63, wave = tid >> 6;
    int ln16 = lane & 15, q = lane >> 4;
    int b = blockIdx.z, h = blockIdx.y, q0 = blockIdx.x * 64;

    const unsigned short* qrow = Qb + ((size_t)(b * 1024 + q0 + wave * 16 + ln16)) * 1024 + h * 64;
    bf16x8 qf0 = *(const bf16x8*)(qrow + q * 8);
    bf16x8 qf1 = *(const bf16x8*)(qrow + 32 + q * 8);

    floatx4 o[4];
    #pragma unroll
    for (int td = 0; td < 4; td++) o[td] = (floatx4){0.f, 0.f, 0.f, 0.f};
    float mrow[4] = {-1e30f, -1e30f, -1e30f, -1e30f};
    float lrow[4] = {0.f, 0.f, 0.f, 0.f};

    const unsigned short* kbase0 = Kb + ((size_t)(b * 1024)) * 1024 + h * 64;
    const unsigned short* vbase0 = Vt + ((size_t)((b * 16 + h) * 64)) * 1024;

    for (int ch = 0; ch < 16; ch++) {
        int l0 = ch * 64;
        __syncthreads();
        #pragma unroll
        for (int it = 0; it < 2; it++) {
            int j = tid + it * 256;
            int row = j >> 3, g = j & 7;
            load_lds16(kbase0 + (size_t)(l0 + row) * 1024 + g * 8, &Ks[j * 8]);
            load_lds16(vbase0 + (size_t)row * 1024 + l0 + g * 8, &Vs[j * 8]);
        }
        __syncthreads();

        floatx4 s[4];
        #pragma unroll
        for (int t = 0; t < 4; t++) {
            s[t] = (floatx4){0.f, 0.f, 0.f, 0.f};
            bf16x8 kf0 = *(const bf16x8*)&Ks[(t * 16 + ln16) * 64 + q * 8];
            bf16x8 kf1 = *(const bf16x8*)&Ks[(t * 16 + ln16) * 64 + 32 + q * 8];
            s[t] = __builtin_amdgcn_mfma_f32_16x16x32_bf16(qf0, kf0, s[t], 0, 0, 0);
            s[t] = __builtin_amdgcn_mfma_f32_16x16x32_bf16(qf1, kf1, s[t], 0, 0, 0);
        }
        float cm[4], rs[4], p[4][4];
        #pragma unroll
        for (int r = 0; r < 4; r++)
            cm[r] = fmaxf(fmaxf(s[0][r], s[1][r]), fmaxf(s[2][r], s[3][r]));
        #pragma unroll
        for (int off = 1; off < 16; off <<= 1) {
            #pragma unroll
            for (int r = 0; r < 4; r++) cm[r] = fmaxf(cm[r], __shfl_xor(cm[r], off));
        }
        #pragma unroll
        for (int r = 0; r < 4; r++) {
            float mnew = fmaxf(mrow[r], cm[r]);
            float alpha = __expf(mrow[r] - mnew);
            mrow[r] = mnew;
            rs[r] = 0.f;
            #pragma unroll
            for (int t = 0; t < 4; t++) {
                p[t][r] = __expf(s[t][r] - mnew);
                rs[r] += p[t][r];
            }
            lrow[r] *= alpha;
            #pragma unroll
            for (int td = 0; td < 4; td++) o[td][r] *= alpha;
        }
        #pragma unroll
        for (int off = 1; off < 16; off <<= 1) {
            #pragma unroll
            for (int r = 0; r < 4; r++) rs[r] += __shfl_xor(rs[r], off);
        }
        #pragma unroll
        for (int r = 0; r < 4; r++) lrow[r] += rs[r];

        short* pw = &Pl[wave][0];
        #pragma unroll
        for (int t = 0; t < 4; t++)
            #pragma unroll
            for (int r = 0; r < 4; r++)
                pw[(q * 4 + r) * 72 + t * 16 + ln16] = (short)f2bf(p[t][r]);
        __syncthreads();
        bf16x8 pf0 = *(const bf16x8*)&pw[ln16 * 72 + q * 8];
        bf16x8 pf1 = *(const bf16x8*)&pw[ln16 * 72 + 32 + q * 8];
        #pragma unroll
        for (int td = 0; td < 4; td++) {
            bf16x8 vf0 = *(const bf16x8*)&Vs[(td * 16 + ln16) * 64 + q * 8];
            bf16x8 vf1 = *(const bf16x8*)&Vs[(td * 16 + ln16) * 64 + 32 + q * 8];
            o[td] = __builtin_amdgcn_mfma_f32_16x16x32_bf16(pf0, vf0, o[td], 0, 0, 0);
            o[td] = __builtin_amdgcn_mfma_f32_16x16x32_bf16(pf1, vf1, o[td], 0, 0, 0);
        }
    }
    #pragma unroll
    for (int td = 0; td < 4; td++) {
        #pragma unroll
        for (int r = 0; r < 4; r++) {
            int row = q0 + wave * 16 + q * 4 + r;
            int col = h * 64 + td * 16 + ln16;
            ob[((size_t)(b * 1024 + row)) * 1024 + col] = f2bf(o[td][r] / lrow[r]);
        }
    }
}

// ------- batched weight transpose + bf16: in fp32 [z][K][N] -> out bf16 [z][N][K] ----
__global__ __launch_bounds__(256) void wtrans_kernel(const float* __restrict__ in,
                                                     unsigned short* __restrict__ out,
                                                     int K, int N) {
    __shared__ float t[64][65];
    int n0 = blockIdx.x * 64, k0 = blockIdx.y * 64, z = blockIdx.z;
    in  += (size_t)z * K * N;
    out += (size_t)z * N * K;
    for (int i = threadIdx.x; i < 4096; i += 256) {
        int kr = i >> 6, nc = i & 63;
        t[kr][nc] = in[(size_t)(k0 + kr) * N + n0 + nc];
    }
    __syncthreads();
    for (int i = threadIdx.x; i < 4096; i += 256) {
        int nr = i >> 6, kc = i & 63;
        out[(size_t)(n0 + nr) * K + k0 + kc] = f2bf(t[kc][nr]);
    }
}

// ------- bf16 MFMA GEMM, BK=64, XOR-swizzled LDS -------------------------------
// C = act(A@B + bias)[+C]; A[M][lda] bf16, Bt[N][lda] bf16.
// SPLITK: blockIdx.z selects K-chunk of size K; raw partials to Cf + z*M*N.
template <int BM, int BN, int WM, int WN, int ACT, bool ADDC, bool OUTBF16, bool SPLITK>
__global__ __launch_bounds__(256) void gemm_bf16(const unsigned short* __restrict__ A,
                                                 const unsigned short* __restrict__ Bt,
                                                 const float* __restrict__ bias,
                                                 float* __restrict__ Cf,
                                                 unsigned short* __restrict__ Cb,
                                                 int M, int N, int K, int lda) {
    constexpr int MT = BM / (WM * 16);
    constexpr int NT = BN / (WN * 16);
    __shared__ short As[BM * 64];
    __shared__ short Bs[BN * 64];
    int tid = threadIdx.x;
    int lane = tid & 63, wave = tid >> 6;
    int wm = wave / WN, wn = wave % WN;
    int ln16 = lane & 15, q = lane >> 4;
    int m0 = blockIdx.y * BM, n0 = blockIdx.x * BN;
    int kOff = SPLITK ? blockIdx.z * K : 0;

    floatx4 acc[MT][NT];
    #pragma unroll
    for (int i = 0; i < MT; i++)
        #pragma unroll
        for (int j = 0; j < NT; j++) acc[i][j] = (floatx4){0.f, 0.f, 0.f, 0.f};

    int kSteps = K >> 6;
    for (int ks = 0; ks < kSteps; ks++) {
        int k0 = kOff + (ks << 6);
        #pragma unroll
        for (int it = 0; it < BM / 32; it++) {
            int i = tid + it * 256;
            int row = i >> 3, gc = (i & 7) ^ (row & 7);   // XOR chunk swizzle
            load_lds16(A + (size_t)(m0 + row) * lda + k0 + gc * 8, &As[i * 8]);
        }
        #pragma unroll
        for (int it = 0; it < BN / 32; it++) {
            int i = tid + it * 256;
            int row = i >> 3, gc = (i & 7) ^ (row & 7);
            load_lds16(Bt + (size_t)(n0 + row) * lda + k0 + gc * 8, &Bs[i * 8]);
        }
        __syncthreads();
        bf16x8 af[2][MT], bf[2][NT];
        #pragma unroll
        for (int h = 0; h < 2; h++) {
            #pragma unroll
            for (int mi = 0; mi < MT; mi++) {
                int row = wm * (BM / WM) + mi * 16 + ln16;
                af[h][mi] = *(const bf16x8*)&As[row * 64 + (((h * 4 + q) ^ (row & 7)) * 8)];
            }
            #pragma unroll
            for (int ni = 0; ni < NT; ni++) {
                int row = wn * (BN / WN) + ni * 16 + ln16;
                bf[h][ni] = *(const bf16x8*)&Bs[row * 64 + (((h * 4 + q) ^ (row & 7)) * 8)];
            }
        }
        #pragma unroll
        for (int h = 0; h < 2; h++)
            #pragma unroll
            for (int mi = 0; mi < MT; mi++)
                #pragma unroll
                for (int ni = 0; ni < NT; ni++)
                    acc[mi][ni] = __builtin_amdgcn_mfma_f32_16x16x32_bf16(af[h][mi], bf[h][ni], acc[mi][ni], 0, 0, 0);
        __syncthreads();
    }

    int q4 = q * 4;
    float* Cp = SPLITK ? (Cf + (size_t)blockIdx.z * M * N) : Cf;
    #pragma unroll
    for (int ni = 0; ni < NT; ni++) {
        int col = n0 + wn * (BN / WN) + ni * 16 + ln16;
        float bv = SPLITK ? 0.f : bias[col];
        #pragma unroll
        for (int mi = 0; mi < MT; mi++) {
            #pragma unroll
            for (int r = 0; r < 4; r++) {
                int row = m0 + wm * (BM / WM) + mi * 16 + q4 + r;
                size_t off = (size_t)row * N + col;
                float v = acc[mi][ni][r] + bv;
                if (!SPLITK && ACT == 1) v = 0.5f * v * (1.f + erff(v * 0.70710678118654752f));
                if (!SPLITK && ADDC) v += Cf[off];
                if (!SPLITK && OUTBF16) Cb[off] = f2bf(v);
                else Cp[off] = v;
            }
        }
    }
}

// ------- split-K reduce: xb += P0 + P1 + bias (fc2 epilogue) -------
__global__ __launch_bounds__(256) void skreduce_kernel(const float* __restrict__ P,
                                                       const float* __restrict__ bias,
                                                       float* __restrict__ xb) {
    int idx = blockIdx.x * 256 + threadIdx.x;          // float4 index, 2048*1024/4
    float4 a = ((const float4*)P)[idx];
    float4 b = ((const float4*)P)[idx + 524288];
    float4 x = ((float4*)xb)[idx];
    const float4 bb = *(const float4*)(bias + (idx & 255) * 4);
    x.x += a.x + b.x + bb.x;
    x.y += a.y + b.y + bb.y;
    x.z += a.z + b.z + bb.z;
    x.w += a.w + b.w + bb.w;
    ((float4*)xb)[idx] = x;
}

// ---------------- unpatchify ----------------
__global__ void unpatchify_kernel(const float* __restrict__ xf, float* __restrict__ img) {
    int idx = blockIdx.x * 256 + threadIdx.x;
    int x = idx & 63, y = (idx >> 6) & 63, ch = (idx >> 12) & 63, b = idx >> 18;
    int hh = y >> 1, ww = x >> 1, p = y & 1, qq = x & 1;
    img[idx] = xf[((size_t)b * 1024 + hh * 32 + ww) * 256 + ch * 4 + p * 2 + qq];
}

// ------- conv1: 64->16, 3x3, pad1, relu -------
__global__ __launch_bounds__(256) void conv1_kernel(const float* __restrict__ img,
                                                    const float* __restrict__ w,
                                                    const float* __restrict__ bias,
                                                    float* __restrict__ out) {
    __shared__ float Ls[64 * 3 * 66];
    __shared__ float Ws[16 * 580];
    int tid = threadIdx.x;
    int y = blockIdx.x, b = blockIdx.y;
    for (int i = tid; i < 9216; i += 256) {
        int oc = i / 576, rem = i % 576;
        Ws[oc * 580 + rem] = w[i];
    }
    for (int i = tid; i < 12288; i += 256) {
        int r = i >> 6, x = i & 63;
        int ic = r / 3, ky = r % 3;
        int yy = y + ky - 1;
        float v = (yy >= 0 && yy < 64) ? img[((size_t)(b * 64 + ic) * 64 + yy) * 64 + x] : 0.f;
        Ls[(ic * 3 + ky) * 66 + x + 1] = v;
        if (x == 0)  Ls[(ic * 3 + ky) * 66 + 0]  = 0.f;
        if (x == 63) Ls[(ic * 3 + ky) * 66 + 65] = 0.f;
    }
    __syncthreads();
    int oc = tid >> 4, xg = (tid & 15) * 4;
    float bv = bias[oc];
    float acc0 = bv, acc1 = bv, acc2 = bv, acc3 = bv;
    for (int ic = 0; ic < 64; ic++) {
        const float* wr = &Ws[oc * 580 + ic * 9];
        float w00 = wr[0], w01 = wr[1], w02 = wr[2];
        float w10 = wr[3], w11 = wr[4], w12 = wr[5];
        float w20 = wr[6], w21 = wr[7], w22 = wr[8];
        const float* l0 = &Ls[(ic * 3 + 0) * 66 + xg];
        const float* l1 = &Ls[(ic * 3 + 1) * 66 + xg];
        const float* l2 = &Ls[(ic * 3 + 2) * 66 + xg];
        float a0 = l0[0], a1 = l0[1], a2 = l0[2], a3 = l0[3], a4 = l0[4], a5 = l0[5];
        float b0 = l1[0], b1 = l1[1], b2 = l1[2], b3 = l1[3], b4 = l1[4], b5 = l1[5];
        float c0 = l2[0], c1 = l2[1], c2 = l2[2], c3 = l2[3], c4 = l2[4], c5 = l2[5];
        acc0 += a0*w00 + a1*w01 + a2*w02 + b0*w10 + b1*w11 + b2*w12 + c0*w20 + c1*w21 + c2*w22;
        acc1 += a1*w00 + a2*w01 + a3*w02 + b1*w10 + b2*w11 + b3*w12 + c1*w20 + c2*w21 + c3*w22;
        acc2 += a2*w00 + a3*w01 + a4*w02 + b2*w10 + b3*w11 + b4*w12 + c2*w20 + c3*w21 + c4*w22;
        acc3 += a3*w00 + a4*w01 + a5*w02 + b3*w10 + b4*w11 + b5*w12 + c3*w20 + c4*w21 + c5*w22;
    }
    float* op = out + (((size_t)(b * 16 + oc) * 64 + y) * 64 + xg);
    op[0] = fmaxf(acc0, 0.f);
    op[1] = fmaxf(acc1, 0.f);
    op[2] = fmaxf(acc2, 0.f);
    op[3] = fmaxf(acc3, 0.f);
}

// ------- conv2: 16->3, 3x3, pad1 -------
__global__ __launch_bounds__(256) void conv2_kernel(const float* __restrict__ in,
                                                    const float* __restrict__ w,
                                                    const float* __restrict__ bias,
                                                    float* __restrict__ out) {
    __shared__ float Ls[16 * 3 * 66];
    __shared__ float Ws[3 * 160];
    int tid = threadIdx.x;
    int y = blockIdx.x, b = blockIdx.y;
    for (int i = tid; i < 432; i += 256) {
        int oc = i / 144, rem = i % 144;
        Ws[oc * 160 + rem] = w[i];
    }
    for (int i = tid; i < 3072; i += 256) {
        int r = i >> 6, x = i & 63;
        int ic = r / 3, ky = r % 3;
        int yy = y + ky - 1;
        float v = (yy >= 0 && yy < 64) ? in[((size_t)(b * 16 + ic) * 64 + yy) * 64 + x] : 0.f;
        Ls[(ic * 3 + ky) * 66 + x + 1] = v;
        if (x == 0)  Ls[(ic * 3 + ky) * 66 + 0]  = 0.f;
        if (x == 63) Ls[(ic * 3 + ky) * 66 + 65] = 0.f;
    }
    __syncthreads();
    int oc = tid >> 6, x = tid & 63;
    if (oc < 3) {
        float acc = bias[oc];
        for (int ic = 0; ic < 16; ic++) {
            const float* wr = &Ws[oc * 160 + ic * 9];
            const float* l0 = &Ls[(ic * 3 + 0) * 66 + x];
            const float* l1 = &Ls[(ic * 3 + 1) * 66 + x];
            const float* l2 = &Ls[(ic * 3 + 2) * 66 + x];
            acc += l0[0]*wr[0] + l0[1]*wr[1] + l0[2]*wr[2]
                 + l1[0]*wr[3] + l1[1]*wr[4] + l1[2]*wr[5]
                 + l2[0]*wr[6] + l2[1]*wr[7] + l2[2]*wr[8];
        }
        out[((size_t)(b * 3 + oc) * 64 + y) * 64 + x] = acc;
    }
}

// ---------------- launch ----------------
extern "C" void kernel_launch(void* const* d_in, const int* in_sizes, int n_in,
                              void* d_out, int out_size, void* d_ws, size_t ws_size,
                              hipStream_t stream) {
    const float* x_in   = (const float*)d_in[0];
    const float* qkv_w  = (const float*)d_in[1];
    const float* qkv_b  = (const float*)d_in[2];
    const float* proj_w = (const float*)d_in[3];
    const float* proj_b = (const float*)d_in[4];
    const float* nq_g   = (const float*)d_in[5];
    const float* nq_b   = (const float*)d_in[6];
    const float* nk_g   = (const float*)d_in[7];
    const float* nk_b   = (const float*)d_in[8];
    const float* n1_g   = (const float*)d_in[9];
    const float* n1_b   = (const float*)d_in[10];
    const float* n2_g   = (const float*)d_in[11];
    const float* n2_b   = (const float*)d_in[12];
    const float* fc1_w  = (const float*)d_in[13];
    const float* fc1_b  = (const float*)d_in[14];
    const float* fc2_w  = (const float*)d_in[15];
    const float* fc2_b  = (const float*)d_in[16];
    const float* fin_w  = (const float*)d_in[17];
    const float* fin_b  = (const float*)d_in[18];
    const float* c1_w   = (const float*)d_in[19];
    const float* c1_b   = (const float*)d_in[20];
    const float* c2_w   = (const float*)d_in[21];
    const float* c2_b   = (const float*)d_in[22];
    float* out = (float*)d_out;

    char* w = (char*)d_ws;
    float* xb           = (float*)w;          w += (size_t)2 * 1024 * 1024 * 4;
    unsigned short* hnb = (unsigned short*)w; w += (size_t)2 * 1024 * 1024 * 2;
    float* qkv          = (float*)w;          w += (size_t)2 * 1024 * 3072 * 4;
    unsigned short* obb = (unsigned short*)w; w += (size_t)2 * 1024 * 1024 * 2;
    unsigned short* mhb = (unsigned short*)w; w += (size_t)2 * 1024 * 4096 * 2;
    float* xf           = (float*)w;          w += (size_t)2 * 1024 * 256 * 4;
    float* img          = (float*)w;          w += (size_t)2 * 64 * 64 * 64 * 4;
    float* c1o          = (float*)w;          w += (size_t)2 * 16 * 64 * 64 * 4;
    unsigned short* Qb  = (unsigned short*)w; w += (size_t)2 * 1024 * 1024 * 2;
    unsigned short* Kb  = (unsigned short*)w; w += (size_t)2 * 1024 * 1024 * 2;
    unsigned short* Vt  = (unsigned short*)w; w += (size_t)2 * 16 * 64 * 1024 * 2;
    float* skb          = (float*)w;          w += (size_t)2 * 2048 * 1024 * 4;   // split-K partials
    unsigned short* WQ  = (unsigned short*)w; w += (size_t)4 * 1024 * 3072 * 2;
    unsigned short* WP  = (unsigned short*)w; w += (size_t)4 * 1024 * 1024 * 2;
    unsigned short* W1  = (unsigned short*)w; w += (size_t)4 * 1024 * 4096 * 2;
    unsigned short* W2  = (unsigned short*)w; w += (size_t)4 * 4096 * 1024 * 2;
    unsigned short* WF  = (unsigned short*)w; w += (size_t)1024 * 256 * 2;

    wtrans_kernel<<<dim3(48, 16, 4), 256, 0, stream>>>(qkv_w, WQ, 1024, 3072);
    wtrans_kernel<<<dim3(16, 16, 4), 256, 0, stream>>>(proj_w, WP, 1024, 1024);
    wtrans_kernel<<<dim3(64, 16, 4), 256, 0, stream>>>(fc1_w, W1, 1024, 4096);
    wtrans_kernel<<<dim3(16, 64, 4), 256, 0, stream>>>(fc2_w, W2, 4096, 1024);
    wtrans_kernel<<<dim3(4, 16, 1), 256, 0, stream>>>(fin_w, WF, 1024, 256);

    posembed_kernel<<<8192, 256, 0, stream>>>(x_in, xb);

    for (int i = 0; i < 4; i++) {
        ln_kernel<<<2048, 256, 0, stream>>>(xb, hnb, n1_g + i * 1024, n1_b + i * 1024, 1e-5f, 1);
        gemm_bf16<64, 128, 2, 2, 0, false, false, false><<<dim3(24, 32), 256, 0, stream>>>(
            hnb, WQ + (size_t)i * 3072 * 1024, qkv_b + i * 3072, qkv, nullptr, 2048, 3072, 1024, 1024);
        qkvprep_kernel<<<dim3(16, 16, 2), 256, 0, stream>>>(
            qkv, nq_g + i * 64, nq_b + i * 64, nk_g + i * 64, nk_b + i * 64, Qb, Kb, Vt);
        attn_mfma<<<dim3(16, 16, 2), 256, 0, stream>>>(Qb, Kb, Vt, obb);
        gemm_bf16<64, 64, 2, 2, 0, true, false, false><<<dim3(16, 32), 256, 0, stream>>>(
            obb, WP + (size_t)i * 1024 * 1024, proj_b + i * 1024, xb, nullptr, 2048, 1024, 1024, 1024);
        ln_kernel<<<2048, 256, 0, stream>>>(xb, hnb, n2_g + i * 1024, n2_b + i * 1024, 1e-5f, 1);
        gemm_bf16<64, 128, 2, 2, 1, false, true, false><<<dim3(32, 32), 256, 0, stream>>>(
            hnb, W1 + (size_t)i * 4096 * 1024, fc1_b + i * 4096, nullptr, mhb, 2048, 4096, 1024, 1024);
        gemm_bf16<64, 64, 2, 2, 0, false, false, true><<<dim3(16, 32, 2), 256, 0, stream>>>(
            mhb, W2 + (size_t)i * 1024 * 4096, fc2_b + i * 1024, skb, nullptr, 2048, 1024, 2048, 4096);
        skreduce_kernel<<<2048, 256, 0, stream>>>(skb, fc2_b + i * 1024, xb);
    }

    ln_kernel<<<2048, 256, 0, stream>>>(xb, hnb, nullptr, nullptr, 1e-6f, 0);
    gemm_bf16<64, 64, 2, 2, 0, false, false, false><<<dim3(4, 32), 256, 0, stream>>>(
        hnb, WF, fin_b, xf, nullptr, 2048, 256, 1024, 1024);
    unpatchify_kernel<<<2048, 256, 0, stream>>>(xf, img);
    conv1_kernel<<<dim3(64, 2), 256, 0, stream>>>(img, c1_w, c1_b, c1o);
    conv2_kernel<<<dim3(64, 2), 256, 0, stream>>>(c1o, c2_w, c2_b, out);
}